// Round 9
// baseline (5324.489 us; speedup 1.0000x reference)
//
#include <hip/hip_runtime.h>

#define LEAK 0.2f
#define EPS  1e-5f
#define TS   503
#define SCOPE_SYS __HIP_MEMORY_SCOPE_SYSTEM
typedef unsigned long long ull;

__device__ __forceinline__ float lrelu(float x){ return x >= 0.f ? x : LEAK * x; }

typedef _Float16 half2v __attribute__((ext_vector_type(2)));

__device__ __forceinline__ unsigned short f2h(float x){
  _Float16 h = (_Float16)x;
  return __builtin_bit_cast(unsigned short, h);
}

__device__ __forceinline__ unsigned packh2(float a, float b){
  return (unsigned)f2h(a) | ((unsigned)f2h(b) << 16);
}

__device__ __forceinline__ float fdot2(unsigned a, unsigned b, float c){
#if __has_builtin(__builtin_amdgcn_fdot2)
  return __builtin_amdgcn_fdot2(__builtin_bit_cast(half2v, a),
                                __builtin_bit_cast(half2v, b), c, false);
#else
  half2v aa = __builtin_bit_cast(half2v, a);
  half2v bb = __builtin_bit_cast(half2v, b);
  return fmaf((float)aa[1], (float)bb[1], fmaf((float)aa[0], (float)bb[0], c));
#endif
}

// block-wide reduce (sum or max), blockDim multiple of 64
template<bool MAXOP>
__device__ __forceinline__ float bred(float v, float* red){
  #pragma unroll
  for (int off = 32; off; off >>= 1){
    float o = __shfl_xor(v, off);
    v = MAXOP ? fmaxf(v, o) : (v + o);
  }
  int nw = blockDim.x >> 6;
  int wv = threadIdx.x >> 6, ln = threadIdx.x & 63;
  __syncthreads();
  if (ln == 0) red[wv] = v;
  __syncthreads();
  if (wv == 0){
    float x = (ln < nw) ? red[ln] : (MAXOP ? -3.402823466e38f : 0.f);
    #pragma unroll
    for (int off = 8; off; off >>= 1){
      float o = __shfl_xor(x, off);
      x = MAXOP ? fmaxf(x, o) : (x + o);
    }
    if (ln == 0) red[0] = x;
  }
  __syncthreads();
  return red[0];
}

// ---- attention ----
__global__ void k_w2(const float* __restrict__ W2w, const float* __restrict__ W2b,
                     const float* __restrict__ hidden, float* __restrict__ w2v){
  int wave = threadIdx.x >> 6, lane = threadIdx.x & 63;
  int row = blockIdx.x*4 + wave;
  const float* wr = W2w + (size_t)row*2048;
  float acc = 0.f;
  #pragma unroll
  for (int k = 0; k < 8; ++k){
    int base = 4*lane + 256*k;
    float4 w = *(const float4*)(wr + base);
    float4 h = *(const float4*)(hidden + base);
    acc = fmaf(w.x,h.x, fmaf(w.y,h.y, fmaf(w.z,h.z, fmaf(w.w,h.w, acc))));
  }
  #pragma unroll
  for (int off = 32; off; off >>= 1) acc += __shfl_xor(acc, off);
  if (lane == 0) w2v[row] = lrelu(acc + W2b[row]);
}

__global__ void k_score(const float* __restrict__ enc, const float* __restrict__ W1w,
                        const float* __restrict__ W1b, const float* __restrict__ Vw,
                        const float* __restrict__ Vb, const float* __restrict__ w2v,
                        float* __restrict__ score){
  __shared__ float sW1[2048*6];
  int tid = threadIdx.x;
  for (int idx = tid; idx < 2048*6; idx += 256) sW1[idx] = W1w[idx];
  __syncthreads();
  int wave = tid >> 6, lane = tid & 63;
  int i = blockIdx.x*4 + wave;
  float e0 = enc[(size_t)i*6+0], e1 = enc[(size_t)i*6+1], e2 = enc[(size_t)i*6+2];
  float e3 = enc[(size_t)i*6+3], e4 = enc[(size_t)i*6+4], e5 = enc[(size_t)i*6+5];
  float acc = 0.f;
  for (int jj = 0; jj < 32; ++jj){
    int j = lane + 64*jj;
    const float* wr = sW1 + j*6;
    float a = fmaf(e0,wr[0], fmaf(e1,wr[1], fmaf(e2,wr[2],
              fmaf(e3,wr[3], fmaf(e4,wr[4], fmaf(e5,wr[5], W1b[j]))))));
    acc = fmaf(lrelu(a), Vw[j], acc);
  }
  #pragma unroll
  for (int off = 32; off; off >>= 1) acc += __shfl_xor(acc, off);
  if (lane == 0) score[i] = acc + w2v[i]*Vw[2048] + Vb[0];
}

__global__ void k_softctx(const float* __restrict__ enc, const float* __restrict__ score,
                          const float* g1, const float* b1, float* __restrict__ ctx){
  __shared__ float red[16];
  int tid = threadIdx.x;
  float s0 = score[tid], s1 = score[tid + 1024];
  float mean = bred<false>(s0 + s1, red) * (1.f/2048.f);
  float d0 = s0 - mean, d1 = s1 - mean;
  float var = bred<false>(d0*d0 + d1*d1, red) * (1.f/2048.f);
  float iv = rsqrtf(var + EPS);
  float g = g1[0], b = b1[0];
  float v0 = lrelu(d0*iv*g + b), v1 = lrelu(d1*iv*g + b);
  float mx = bred<true>(fmaxf(v0, v1), red);
  float e0 = expf(v0 - mx), e1 = expf(v1 - mx);
  float se = bred<false>(e0 + e1, red);
  float w0 = e0/se, w1 = e1/se;
  #pragma unroll
  for (int c = 0; c < 6; ++c){
    ctx[c*2048 + tid]        = enc[(size_t)tid*6 + c] * w0;
    ctx[c*2048 + tid + 1024] = enc[(size_t)(tid+1024)*6 + c] * w1;
  }
}

// ---- CNN ----
__global__ void k_conv(const float* __restrict__ in, int Lin,
                       float* __restrict__ out, int Lout,
                       const float* __restrict__ w, const float* __restrict__ b, int K){
  int idx = blockIdx.x*256 + threadIdx.x;
  if (idx >= 6*Lout) return;
  int o = idx / Lout, x = idx - o*Lout;
  float acc = b[o];
  for (int i = 0; i < 6; ++i){
    const float* ir = in + i*Lin + x;
    const float* wr = w + (o*6 + i)*K;
    for (int k = 0; k < K; ++k) acc = fmaf(ir[k], wr[k], acc);
  }
  out[o*Lout + x] = lrelu(acc);
}

__global__ void k_pool(const float* __restrict__ in, int Lin, float* __restrict__ out, int Lout){
  int idx = blockIdx.x*256 + threadIdx.x;
  if (idx >= 6*Lout) return;
  int o = idx / Lout, x = idx - o*Lout;
  out[idx] = fmaxf(in[o*Lin + 2*x], in[o*Lin + 2*x + 1]);
}

__global__ void k_bn2stats(const float* __restrict__ in, float* m6, float* i6){
  __shared__ float red[16];
  for (int c = 0; c < 6; ++c){
    float s = 0.f, s2 = 0.f;
    for (int i = threadIdx.x; i < 1006; i += 256){
      float v = in[c*1006 + i]; s += v; s2 += v*v;
    }
    s  = bred<false>(s, red);
    s2 = bred<false>(s2, red);
    if (threadIdx.x == 0){
      float m = s / 1006.f;
      float var = s2 / 1006.f - m*m;
      m6[c] = m; i6[c] = rsqrtf(var + EPS);
    }
  }
}

__global__ void k_seq(const float* __restrict__ cb4, const float* m6, const float* i6,
                      const float* g2, const float* b2, float* __restrict__ seq){
  int idx = blockIdx.x*256 + threadIdx.x;
  if (idx >= TS*6) return;
  int c = idx % 6, t = idx / 6;
  float m = m6[c], iv = i6[c], g = g2[c], b = b2[c];
  float v0 = (cb4[c*1006 + 2*t]     - m)*iv*g + b;
  float v1 = (cb4[c*1006 + 2*t + 1] - m)*iv*g + b;
  seq[idx] = fmaxf(v0, v1);
}

__global__ void k_gihat(const float* __restrict__ seq, const float* __restrict__ Wi,
                        const float* __restrict__ bi, float* __restrict__ gihat){
  int row = blockIdx.x*256 + threadIdx.x;   // < 6144
  int t = blockIdx.y;
  const float* s = seq + t*6;
  const float* w = Wi + (size_t)row*6;
  float v = fmaf(s[0],w[0], fmaf(s[1],w[1], fmaf(s[2],w[2],
            fmaf(s[3],w[3], fmaf(s[4],w[4], fmaf(s[5],w[5], bi[row]))))));
  gihat[(size_t)t*6144 + row] = v;
}

// ---- GRU: 256 WGs, ZERO-barrier steps, wave-autonomous tagged exchange ----
// Lane owns the CONTIGUOUS h segment [32*lane, 32*lane+32): its 16 u64 slots
// {tag=t | f16x2 pair} double as the h-load -- the poll unpacks arrived pairs
// straight into registers. No LDS h staging, no __syncthreads in the t-loop;
// per wave the 16 slots are one contiguous 8KB block (line-coalesced at the
// MALL). Weights live in LDS in a bank-conflict-free physical layout: granule
// (lane,k) of row lr at byte lr*4096 + k*1024 + 16*lane (16B stride across
// lanes; the naive 64B stride would be a 32-way conflict). WAR safety without
// barriers: a wave exits its poll only after observing ALL 1024 pairs tagged t,
// so any wave publishing step t+2 (overwriting parity t&1) implies every wave
// finished reading parity t&1 at step t+1 -- the slack-2 induction holds at
// wave granularity. Stale tags cleared by a 16KB memset per launch.
#define GRU_SMEM (24*2048*2)

__global__ void __launch_bounds__(256, 1)
k_gru(const float* __restrict__ Wh, const float* __restrict__ bh,
      const float* __restrict__ hidden, const float* __restrict__ gihat,
      ull* hbuf, float* __restrict__ xs, float* __restrict__ dout){
  extern __shared__ char smem[];
  ushort* Wl = (ushort*)smem;                 // [24][2048] f16, swizzled
  const int tid = threadIdx.x, wg = blockIdx.x;
  const int lane = tid & 63, w = tid >> 6;
  const int hbase = wg << 3;

  // stage weights into the swizzled physical layout:
  // physical f16 index q in row: k=q>>9, i=(q>>3)&63, e=q&7 -> logical col
  // 32*i + 8*k + e. Local row lr = 6*wv + kk: gate kk>>1, output kk&1.
  for (int idx = tid; idx < 24*2048; idx += 256){
    int lr = idx >> 11, q = idx & 2047;
    int k = q >> 9, i = (q >> 3) & 63, e = q & 7;
    int col = 32*i + 8*k + e;
    int wv = lr/6, kk = lr - 6*wv, gate = kk >> 1, o = kk & 1;
    int grow = (gate << 11) + hbase + 2*wv + o;
    Wl[idx] = f2h(Wh[(size_t)grow*2048 + col]);
  }
  float bhr = 0.f, bhz = 0.f, bhn = 0.f, hold = 0.f;
  if (lane < 2){
    int o = hbase + 2*w + lane;
    bhr = bh[o]; bhz = bh[2048 + o]; bhn = bh[4096 + o];
    hold = hidden[o];
  }
  __syncthreads();   // weights staged (the ONLY barrier)

  uint4 hf[4];       // 16 f16x2 pairs = h[32*lane .. 32*lane+32)
  for (int t = 0; t < TS; ++t){
    // per-step input-gate biases for this wave's 2 outputs (hide under poll)
    float gr = 0.f, gz = 0.f, gn = 0.f;
    if (lane < 2){
      const float* gp = gihat + (size_t)t*6144 + hbase + 2*w + lane;
      gr = gp[0]; gz = gp[2048]; gn = gp[4096];
    }
    if (t == 0){
      const float* hp = hidden + 32*lane;
      #pragma unroll
      for (int k = 0; k < 4; ++k){
        float4 a = *(const float4*)(hp + 8*k);
        float4 b = *(const float4*)(hp + 8*k + 4);
        hf[k] = make_uint4(packh2(a.x, a.y), packh2(a.z, a.w),
                           packh2(b.x, b.y), packh2(b.z, b.w));
      }
    } else {
      const ull* src = hbuf + (size_t)((t - 1) & 1)*1024 + 16*lane;
      const unsigned expect = (unsigned)t;
      unsigned done = 0;
      for (;;){
        ull v[16];
        #pragma unroll
        for (int j = 0; j < 16; ++j)
          if (!((done >> j) & 1u))
            v[j] = __hip_atomic_load(src + j, __ATOMIC_RELAXED, SCOPE_SYS);
        unsigned nd = done;
        #pragma unroll
        for (int j = 0; j < 16; ++j)
          if (!((done >> j) & 1u) && (unsigned)(v[j] >> 32) == expect){
            nd |= (1u << j);
            ((unsigned*)hf)[j] = (unsigned)v[j];
          }
        if (__all(nd == 0xFFFFu)){ break; }
        done = nd;
        __builtin_amdgcn_s_sleep(1);
      }
    }

    // 6 dot rows over this lane's 32 h values; weights via conflict-free LDS
    float acc[6];
    #pragma unroll
    for (int rr = 0; rr < 6; ++rr){
      int lr = 6*w + rr;
      const char* wrow = (const char*)Wl + lr*4096 + 16*lane;
      float a = 0.f;
      #pragma unroll
      for (int k = 0; k < 4; ++k){
        uint4 wv4 = *(const uint4*)(wrow + (k << 10));
        a = fdot2(wv4.x, hf[k].x, a);
        a = fdot2(wv4.y, hf[k].y, a);
        a = fdot2(wv4.z, hf[k].z, a);
        a = fdot2(wv4.w, hf[k].w, a);
      }
      #pragma unroll
      for (int off = 32; off; off >>= 1) a += __shfl_xor(a, off);
      acc[rr] = a;
    }
    // lanes 0,1 combine their output in parallel
    float hnew = 0.f;
    if (lane < 2){
      float r  = 1.f/(1.f + expf(-(gr + bhr + acc[0 + lane])));
      float z  = 1.f/(1.f + expf(-(gz + bhz + acc[2 + lane])));
      float ng = tanhf(gn + r*(acc[4 + lane] + bhn));
      hnew = (1.f - z)*ng + z*hold;
    }
    float hn1 = __shfl(hnew, 1);
    if (lane == 0){
      ull pv = ((ull)(unsigned)(t + 1) << 32) | (ull)packh2(hnew, hn1);
      __hip_atomic_store(hbuf + (size_t)(t & 1)*1024 + 4*wg + w, pv,
                         __ATOMIC_RELAXED, SCOPE_SYS);
    }
    if (lane < 2){
      xs[(size_t)t*2048 + hbase + 2*w + lane] = hnew;
      if (t == TS - 1) dout[4 + hbase + 2*w + lane] = hnew;
      hold = hnew;
    }
  }
}

// ---- head ----
__global__ void k_lin1(const float* __restrict__ xs, const float* __restrict__ W,
                       const float* __restrict__ B, float* __restrict__ y1){
  __shared__ float xT[32][36];
  __shared__ float wT[32][36];
  int tid = threadIdx.x;
  int m0 = blockIdx.y*32, n0 = blockIdx.x*32;
  int lm = tid >> 3, lk = (tid & 7)*4;
  int tx = tid & 15, ty = tid >> 4;
  float acc00=0.f, acc01=0.f, acc10=0.f, acc11=0.f;
  for (int k0 = 0; k0 < 2048; k0 += 32){
    float4 xv = make_float4(0.f,0.f,0.f,0.f);
    int tt = m0 + lm;
    if (tt < TS) xv = *(const float4*)(xs + (size_t)tt*2048 + k0 + lk);
    xT[lk+0][lm] = lrelu(xv.x); xT[lk+1][lm] = lrelu(xv.y);
    xT[lk+2][lm] = lrelu(xv.z); xT[lk+3][lm] = lrelu(xv.w);
    float4 wv = make_float4(0.f,0.f,0.f,0.f);
    int jj = n0 + lm;
    if (jj < 400) wv = *(const float4*)(W + (size_t)jj*2048 + k0 + lk);
    wT[lk+0][lm] = wv.x; wT[lk+1][lm] = wv.y; wT[lk+2][lm] = wv.z; wT[lk+3][lm] = wv.w;
    __syncthreads();
    #pragma unroll
    for (int k = 0; k < 32; ++k){
      float2 a = *(const float2*)&xT[k][2*ty];
      float2 b = *(const float2*)&wT[k][2*tx];
      acc00 = fmaf(a.x, b.x, acc00); acc01 = fmaf(a.x, b.y, acc01);
      acc10 = fmaf(a.y, b.x, acc10); acc11 = fmaf(a.y, b.y, acc11);
    }
    __syncthreads();
  }
  int t0 = m0 + 2*ty, j0 = n0 + 2*tx;
  if (t0 < TS){
    if (j0 < 400)   y1[t0*400 + j0]   = acc00 + B[j0];
    if (j0+1 < 400) y1[t0*400 + j0+1] = acc01 + B[j0+1];
  }
  if (t0+1 < TS){
    if (j0 < 400)   y1[(t0+1)*400 + j0]   = acc10 + B[j0];
    if (j0+1 < 400) y1[(t0+1)*400 + j0+1] = acc11 + B[j0+1];
  }
}

__global__ void k_bn3p(const float* __restrict__ y1, float* __restrict__ part){
  __shared__ float red[16];
  float s = 0.f, s2 = 0.f;
  for (int idx = blockIdx.x*256 + threadIdx.x; idx < TS*400; idx += 64*256){
    float v = y1[idx]; s += v; s2 += v*v;
  }
  s  = bred<false>(s, red);
  s2 = bred<false>(s2, red);
  if (threadIdx.x == 0){ part[blockIdx.x] = s; part[64 + blockIdx.x] = s2; }
}

__global__ void k_bn3f(const float* __restrict__ part, float* __restrict__ stats){
  int ln = threadIdx.x;
  float s = part[ln], s2 = part[64 + ln];
  #pragma unroll
  for (int off = 32; off; off >>= 1){ s += __shfl_xor(s, off); s2 += __shfl_xor(s2, off); }
  if (ln == 0){
    float m = s / (float)(TS*400);
    float var = s2 / (float)(TS*400) - m*m;
    stats[0] = m; stats[1] = rsqrtf(var + EPS);
  }
}

__global__ void k_x2(const float* __restrict__ y1, const float* __restrict__ stats,
                     const float* g3, const float* b3, const float* __restrict__ l2w,
                     const float* l2b, float* __restrict__ x2){
  int t = blockIdx.x, ln = threadIdx.x;
  float m = stats[0], iv = stats[1], g = g3[0], b = b3[0];
  float acc = 0.f;
  for (int j = ln; j < 400; j += 64)
    acc = fmaf(lrelu((y1[t*400 + j] - m)*iv*g + b), l2w[j], acc);
  #pragma unroll
  for (int off = 32; off; off >>= 1) acc += __shfl_xor(acc, off);
  if (ln == 0) x2[t] = lrelu(acc + l2b[0]);
}

__global__ void k_head(const float* __restrict__ x2, const float* __restrict__ last,
                       const float* __restrict__ l3w, const float* __restrict__ l3b,
                       const float* __restrict__ l4w, const float* __restrict__ l4b,
                       float* __restrict__ out){
  __shared__ float o1[50];
  int tid = threadIdx.x;
  if (tid < 50){
    float acc = l3b[tid];
    const float* wr = l3w + tid*507;
    for (int i = 0; i < TS; ++i) acc = fmaf(x2[i], wr[i], acc);
    for (int i = 0; i < 4; ++i)  acc = fmaf(last[i], wr[TS + i], acc);
    o1[tid] = lrelu(acc);
  }
  __syncthreads();
  if (tid < 4){
    float acc = l4b[tid];
    const float* wr = l4w + tid*50;
    for (int k = 0; k < 50; ++k) acc = fmaf(o1[k], wr[k], acc);
    out[tid] = acc;
  }
}

// ---- workspace layout (bytes) ----
#define OFF_BN2M    1024u
#define OFF_BN2I    1056u
#define OFF_BN3P    2048u
#define OFF_BN3S    2560u
#define OFF_W2      4096u
#define OFF_SCORE   12288u
#define OFF_X2      20480u
#define OFF_CTX     24576u
#define OFF_CB1     73728u      // cb1 (dead after conv2) is overlaid by hbuf (16KB)
#define OFF_HBUF    73728u
#define OFF_CB2     122880u
#define OFF_CP1     172032u
#define OFF_CB3     196608u
#define OFF_CB4     221184u
#define OFF_SEQ     245760u
#define OFF_GIHAT   274432u
#define OFF_XS      12636160u
#define OFF_Y1      16756736u

extern "C" void kernel_launch(void* const* d_in, const int* in_sizes, int n_in,
                              void* d_out, int out_size, void* d_ws, size_t ws_size,
                              hipStream_t stream){
  const float* last   = (const float*)d_in[0];
  const float* hidden = (const float*)d_in[1];
  const float* enc    = (const float*)d_in[2];
  const float* W1w = (const float*)d_in[3];
  const float* W1b = (const float*)d_in[4];
  const float* W2w = (const float*)d_in[5];
  const float* W2b = (const float*)d_in[6];
  const float* Vw  = (const float*)d_in[7];
  const float* Vb  = (const float*)d_in[8];
  const float* g1  = (const float*)d_in[9];
  const float* b1  = (const float*)d_in[10];
  const float* c1w = (const float*)d_in[11]; const float* c1b = (const float*)d_in[12];
  const float* c2w = (const float*)d_in[13]; const float* c2b = (const float*)d_in[14];
  const float* c3w = (const float*)d_in[15]; const float* c3b = (const float*)d_in[16];
  const float* c4w = (const float*)d_in[17]; const float* c4b = (const float*)d_in[18];
  const float* g2  = (const float*)d_in[19]; const float* b2  = (const float*)d_in[20];
  const float* Wi  = (const float*)d_in[21]; const float* Wh  = (const float*)d_in[22];
  const float* bi  = (const float*)d_in[23]; const float* bhp = (const float*)d_in[24];
  const float* l1w = (const float*)d_in[25]; const float* l1b = (const float*)d_in[26];
  const float* g3  = (const float*)d_in[27]; const float* b3  = (const float*)d_in[28];
  const float* l2w = (const float*)d_in[29]; const float* l2b = (const float*)d_in[30];
  const float* l3w = (const float*)d_in[31]; const float* l3b = (const float*)d_in[32];
  const float* l4w = (const float*)d_in[33]; const float* l4b = (const float*)d_in[34];
  float* out = (float*)d_out;
  char* ws = (char*)d_ws;

  float* bn2m  = (float*)(ws + OFF_BN2M);
  float* bn2i  = (float*)(ws + OFF_BN2I);
  float* bn3p  = (float*)(ws + OFF_BN3P);
  float* bn3s  = (float*)(ws + OFF_BN3S);
  float* w2v   = (float*)(ws + OFF_W2);
  float* score = (float*)(ws + OFF_SCORE);
  float* x2    = (float*)(ws + OFF_X2);
  float* ctx   = (float*)(ws + OFF_CTX);
  float* cb1   = (float*)(ws + OFF_CB1);
  ull*   hbuf  = (ull*)(ws + OFF_HBUF);
  float* cb2   = (float*)(ws + OFF_CB2);
  float* cp1   = (float*)(ws + OFF_CP1);
  float* cb3   = (float*)(ws + OFF_CB3);
  float* cb4   = (float*)(ws + OFF_CB4);
  float* seq   = (float*)(ws + OFF_SEQ);
  float* gihat = (float*)(ws + OFF_GIHAT);
  float* xs    = (float*)(ws + OFF_XS);
  float* y1    = (float*)(ws + OFF_Y1);

  k_w2<<<512, 256, 0, stream>>>(W2w, W2b, hidden, w2v);
  k_score<<<512, 256, 0, stream>>>(enc, W1w, W1b, Vw, Vb, w2v, score);
  k_softctx<<<1, 1024, 0, stream>>>(enc, score, g1, b1, ctx);

  k_conv<<<(6*2038 + 255)/256, 256, 0, stream>>>(ctx, 2048, cb1, 2038, c1w, c1b, 11);
  k_conv<<<(6*2028 + 255)/256, 256, 0, stream>>>(cb1, 2038, cb2, 2028, c2w, c2b, 11);
  // cb1 dead from here; clear stale tags in the overlaid hbuf (stream-ordered)
  hipMemsetAsync(hbuf, 0, 2*1024*sizeof(ull), stream);
  k_pool<<<(6*1014 + 255)/256, 256, 0, stream>>>(cb2, 2028, cp1, 1014);
  k_conv<<<(6*1010 + 255)/256, 256, 0, stream>>>(cp1, 1014, cb3, 1010, c3w, c3b, 5);
  k_conv<<<(6*1006 + 255)/256, 256, 0, stream>>>(cb3, 1010, cb4, 1006, c4w, c4b, 5);
  k_bn2stats<<<1, 256, 0, stream>>>(cb4, bn2m, bn2i);
  k_seq<<<12, 256, 0, stream>>>(cb4, bn2m, bn2i, g2, b2, seq);
  k_gihat<<<dim3(24, TS), 256, 0, stream>>>(seq, Wi, bi, gihat);

  hipFuncSetAttribute((const void*)k_gru, hipFuncAttributeMaxDynamicSharedMemorySize,
                      (int)GRU_SMEM);
  void* kargs[7] = {(void*)&Wh, (void*)&bhp, (void*)&hidden, (void*)&gihat,
                    (void*)&hbuf, (void*)&xs, (void*)&out};
  hipLaunchCooperativeKernel((const void*)k_gru, dim3(256), dim3(256), kargs,
                             (unsigned)GRU_SMEM, stream);

  k_lin1<<<dim3(13, 16), 256, 0, stream>>>(xs, l1w, l1b, y1);
  k_bn3p<<<64, 256, 0, stream>>>(y1, bn3p);
  k_bn3f<<<1, 64, 0, stream>>>(bn3p, bn3s);
  k_x2<<<TS, 64, 0, stream>>>(y1, bn3s, g3, b3, l2w, l2b, x2);
  k_head<<<1, 64, 0, stream>>>(x2, last, l3w, l3b, l4w, l4b, out);
}

// Round 10
// 2574.137 us; speedup vs baseline: 2.0685x; 2.0685x over previous
//
#include <hip/hip_runtime.h>

#define LEAK 0.2f
#define EPS  1e-5f
#define TS   503
#define SCOPE_SYS __HIP_MEMORY_SCOPE_SYSTEM
typedef unsigned long long ull;

__device__ __forceinline__ float lrelu(float x){ return x >= 0.f ? x : LEAK * x; }

typedef _Float16 half2v __attribute__((ext_vector_type(2)));

__device__ __forceinline__ unsigned short f2h(float x){
  _Float16 h = (_Float16)x;
  return __builtin_bit_cast(unsigned short, h);
}

__device__ __forceinline__ float fdot2(unsigned a, unsigned b, float c){
#if __has_builtin(__builtin_amdgcn_fdot2)
  return __builtin_amdgcn_fdot2(__builtin_bit_cast(half2v, a),
                                __builtin_bit_cast(half2v, b), c, false);
#else
  half2v aa = __builtin_bit_cast(half2v, a);
  half2v bb = __builtin_bit_cast(half2v, b);
  return fmaf((float)aa[1], (float)bb[1], fmaf((float)aa[0], (float)bb[0], c));
#endif
}

// block-wide reduce (sum or max), blockDim multiple of 64
template<bool MAXOP>
__device__ __forceinline__ float bred(float v, float* red){
  #pragma unroll
  for (int off = 32; off; off >>= 1){
    float o = __shfl_xor(v, off);
    v = MAXOP ? fmaxf(v, o) : (v + o);
  }
  int nw = blockDim.x >> 6;
  int wv = threadIdx.x >> 6, ln = threadIdx.x & 63;
  __syncthreads();
  if (ln == 0) red[wv] = v;
  __syncthreads();
  if (wv == 0){
    float x = (ln < nw) ? red[ln] : (MAXOP ? -3.402823466e38f : 0.f);
    #pragma unroll
    for (int off = 8; off; off >>= 1){
      float o = __shfl_xor(x, off);
      x = MAXOP ? fmaxf(x, o) : (x + o);
    }
    if (ln == 0) red[0] = x;
  }
  __syncthreads();
  return red[0];
}

// ---- attention ----
__global__ void k_w2(const float* __restrict__ W2w, const float* __restrict__ W2b,
                     const float* __restrict__ hidden, float* __restrict__ w2v){
  int wave = threadIdx.x >> 6, lane = threadIdx.x & 63;
  int row = blockIdx.x*4 + wave;
  const float* wr = W2w + (size_t)row*2048;
  float acc = 0.f;
  #pragma unroll
  for (int k = 0; k < 8; ++k){
    int base = 4*lane + 256*k;
    float4 w = *(const float4*)(wr + base);
    float4 h = *(const float4*)(hidden + base);
    acc = fmaf(w.x,h.x, fmaf(w.y,h.y, fmaf(w.z,h.z, fmaf(w.w,h.w, acc))));
  }
  #pragma unroll
  for (int off = 32; off; off >>= 1) acc += __shfl_xor(acc, off);
  if (lane == 0) w2v[row] = lrelu(acc + W2b[row]);
}

__global__ void k_score(const float* __restrict__ enc, const float* __restrict__ W1w,
                        const float* __restrict__ W1b, const float* __restrict__ Vw,
                        const float* __restrict__ Vb, const float* __restrict__ w2v,
                        float* __restrict__ score){
  __shared__ float sW1[2048*6];
  int tid = threadIdx.x;
  for (int idx = tid; idx < 2048*6; idx += 256) sW1[idx] = W1w[idx];
  __syncthreads();
  int wave = tid >> 6, lane = tid & 63;
  int i = blockIdx.x*4 + wave;
  float e0 = enc[(size_t)i*6+0], e1 = enc[(size_t)i*6+1], e2 = enc[(size_t)i*6+2];
  float e3 = enc[(size_t)i*6+3], e4 = enc[(size_t)i*6+4], e5 = enc[(size_t)i*6+5];
  float acc = 0.f;
  for (int jj = 0; jj < 32; ++jj){
    int j = lane + 64*jj;
    const float* wr = sW1 + j*6;
    float a = fmaf(e0,wr[0], fmaf(e1,wr[1], fmaf(e2,wr[2],
              fmaf(e3,wr[3], fmaf(e4,wr[4], fmaf(e5,wr[5], W1b[j]))))));
    acc = fmaf(lrelu(a), Vw[j], acc);
  }
  #pragma unroll
  for (int off = 32; off; off >>= 1) acc += __shfl_xor(acc, off);
  if (lane == 0) score[i] = acc + w2v[i]*Vw[2048] + Vb[0];
}

__global__ void k_softctx(const float* __restrict__ enc, const float* __restrict__ score,
                          const float* g1, const float* b1, float* __restrict__ ctx){
  __shared__ float red[16];
  int tid = threadIdx.x;
  float s0 = score[tid], s1 = score[tid + 1024];
  float mean = bred<false>(s0 + s1, red) * (1.f/2048.f);
  float d0 = s0 - mean, d1 = s1 - mean;
  float var = bred<false>(d0*d0 + d1*d1, red) * (1.f/2048.f);
  float iv = rsqrtf(var + EPS);
  float g = g1[0], b = b1[0];
  float v0 = lrelu(d0*iv*g + b), v1 = lrelu(d1*iv*g + b);
  float mx = bred<true>(fmaxf(v0, v1), red);
  float e0 = expf(v0 - mx), e1 = expf(v1 - mx);
  float se = bred<false>(e0 + e1, red);
  float w0 = e0/se, w1 = e1/se;
  #pragma unroll
  for (int c = 0; c < 6; ++c){
    ctx[c*2048 + tid]        = enc[(size_t)tid*6 + c] * w0;
    ctx[c*2048 + tid + 1024] = enc[(size_t)(tid+1024)*6 + c] * w1;
  }
}

// ---- CNN ----
__global__ void k_conv(const float* __restrict__ in, int Lin,
                       float* __restrict__ out, int Lout,
                       const float* __restrict__ w, const float* __restrict__ b, int K){
  int idx = blockIdx.x*256 + threadIdx.x;
  if (idx >= 6*Lout) return;
  int o = idx / Lout, x = idx - o*Lout;
  float acc = b[o];
  for (int i = 0; i < 6; ++i){
    const float* ir = in + i*Lin + x;
    const float* wr = w + (o*6 + i)*K;
    for (int k = 0; k < K; ++k) acc = fmaf(ir[k], wr[k], acc);
  }
  out[o*Lout + x] = lrelu(acc);
}

__global__ void k_pool(const float* __restrict__ in, int Lin, float* __restrict__ out, int Lout){
  int idx = blockIdx.x*256 + threadIdx.x;
  if (idx >= 6*Lout) return;
  int o = idx / Lout, x = idx - o*Lout;
  out[idx] = fmaxf(in[o*Lin + 2*x], in[o*Lin + 2*x + 1]);
}

__global__ void k_bn2stats(const float* __restrict__ in, float* m6, float* i6){
  __shared__ float red[16];
  for (int c = 0; c < 6; ++c){
    float s = 0.f, s2 = 0.f;
    for (int i = threadIdx.x; i < 1006; i += 256){
      float v = in[c*1006 + i]; s += v; s2 += v*v;
    }
    s  = bred<false>(s, red);
    s2 = bred<false>(s2, red);
    if (threadIdx.x == 0){
      float m = s / 1006.f;
      float var = s2 / 1006.f - m*m;
      m6[c] = m; i6[c] = rsqrtf(var + EPS);
    }
  }
}

__global__ void k_seq(const float* __restrict__ cb4, const float* m6, const float* i6,
                      const float* g2, const float* b2, float* __restrict__ seq){
  int idx = blockIdx.x*256 + threadIdx.x;
  if (idx >= TS*6) return;
  int c = idx % 6, t = idx / 6;
  float m = m6[c], iv = i6[c], g = g2[c], b = b2[c];
  float v0 = (cb4[c*1006 + 2*t]     - m)*iv*g + b;
  float v1 = (cb4[c*1006 + 2*t + 1] - m)*iv*g + b;
  seq[idx] = fmaxf(v0, v1);
}

__global__ void k_gihat(const float* __restrict__ seq, const float* __restrict__ Wi,
                        const float* __restrict__ bi, float* __restrict__ gihat){
  int row = blockIdx.x*256 + threadIdx.x;   // < 6144
  int t = blockIdx.y;
  const float* s = seq + t*6;
  const float* w = Wi + (size_t)row*6;
  float v = fmaf(s[0],w[0], fmaf(s[1],w[1], fmaf(s[2],w[2],
            fmaf(s[3],w[3], fmaf(s[4],w[4], fmaf(s[5],w[5], bi[row]))))));
  gihat[(size_t)t*6144 + row] = v;
}

// ---- GRU: 256 WGs, LDS f16 Wh, tagged u32 publish (r5 protocol, leaner) ----
// Each published slot is ONE u32 {tag16=t+1 | f16} stored lane-autonomously
// (lanes 0,1 of each wave) with a SYSTEM-scope relaxed atomic (MALL coherence
// point, no cache maintenance, no eviction gating). vs r5: no __shfl/64-bit
// pack before the store, half the publish bytes. Consumer thread tid polls its
// 8 u32 slots (same 32B/thread sweep footprint as r5 -- the measured optimum;
// r9's 4x footprint and r7/r6's alternatives all regressed), no sleep between
// sweeps. detect==read, one round trip. WAR over the 2-parity buffer: a WG
// publishes step t only after its post-poll barrier, i.e. after all its reads
// of step t-1; publishing t+2 (same parity) implies every WG finished reading
// parity t&1. Stale tags cleared by a 16KB memset per launch.
#define GRU_SMEM (24*2048*2 + 1024*4)

__global__ void __launch_bounds__(256, 1)
k_gru(const float* __restrict__ Wh, const float* __restrict__ bh,
      const float* __restrict__ hidden, const float* __restrict__ gihat,
      unsigned* hbuf, float* __restrict__ xs, float* __restrict__ dout){
  extern __shared__ char smem[];
  ushort* Wl    = (ushort*)smem;                 // [24][2048] f16
  unsigned* h2  = (unsigned*)(smem + 24*2048*2); // [1024] f16x2 pairs
  const int tid = threadIdx.x, wg = blockIdx.x;
  const int lane = tid & 63, w = tid >> 6;
  const int hbase = wg << 3;

  // stage weights: wave w's local rows 6w+k, k=0..5 -> gate k>>1, output k&1
  for (int idx = tid; idx < 24*2048; idx += 256){
    int lr = idx >> 11, col = idx & 2047;
    int wv = lr/6, k = lr - 6*wv, gate = k >> 1, o = k & 1;
    int grow = (gate << 11) + hbase + 2*wv + o;
    Wl[idx] = f2h(Wh[(size_t)grow*2048 + col]);
  }
  float bhr = 0.f, bhz = 0.f, bhn = 0.f, hold = 0.f;
  if (lane < 2){
    int o = hbase + 2*w + lane;
    bhr = bh[o]; bhz = bh[2048 + o]; bhn = bh[4096 + o];
    hold = hidden[o];
  }
  __syncthreads();

  for (int t = 0; t < TS; ++t){
    // per-step input-gate biases for this wave's 2 outputs (hide under poll)
    float gr = 0.f, gz = 0.f, gn = 0.f;
    if (lane < 2){
      const float* gp = gihat + (size_t)t*6144 + hbase + 2*w + lane;
      gr = gp[0]; gz = gp[2048]; gn = gp[4096];
    }
    // acquire h[t-1]: thread tid owns u32 slots 8*tid..8*tid+7 (h[8t..8t+8))
    if (t == 0){
      const float4* hp = (const float4*)(hidden + 8*tid);
      float4 a = hp[0], b = hp[1];
      unsigned p0 = (unsigned)f2h(a.x) | ((unsigned)f2h(a.y) << 16);
      unsigned p1 = (unsigned)f2h(a.z) | ((unsigned)f2h(a.w) << 16);
      unsigned p2 = (unsigned)f2h(b.x) | ((unsigned)f2h(b.y) << 16);
      unsigned p3 = (unsigned)f2h(b.z) | ((unsigned)f2h(b.w) << 16);
      *(uint4*)(h2 + 4*tid) = make_uint4(p0, p1, p2, p3);
    } else {
      const unsigned* src = hbuf + (size_t)((t - 1) & 1)*2048 + 8*tid;
      const unsigned expect = (unsigned)t;   // tag16 of step t-1's publish
      unsigned v[8];
      unsigned done = 0;
      for (;;){
        #pragma unroll
        for (int j = 0; j < 8; ++j)
          if (!((done >> j) & 1u))
            v[j] = __hip_atomic_load(src + j, __ATOMIC_RELAXED, SCOPE_SYS);
        unsigned nd = done;
        #pragma unroll
        for (int j = 0; j < 8; ++j)
          if (!((done >> j) & 1u) && (v[j] >> 16) == expect) nd |= (1u << j);
        if (nd == 255u) break;
        done = nd;
      }
      unsigned p0 = (v[0] & 0xffffu) | (v[1] << 16);
      unsigned p1 = (v[2] & 0xffffu) | (v[3] << 16);
      unsigned p2 = (v[4] & 0xffffu) | (v[5] << 16);
      unsigned p3 = (v[6] & 0xffffu) | (v[7] << 16);
      *(uint4*)(h2 + 4*tid) = make_uint4(p0, p1, p2, p3);
    }
    __syncthreads();

    // per-lane h fragment: 4 x b128 = 32 h values as 16 f16-pairs
    uint4 hf[4];
    #pragma unroll
    for (int k = 0; k < 4; ++k)
      hf[k] = *(const uint4*)((const char*)h2 + 16*lane + 1024*k);
    // 6 dot rows; full butterfly so every lane ends with all 6 sums
    float acc[6];
    #pragma unroll
    for (int rr = 0; rr < 6; ++rr){
      int lr = 6*w + rr;
      const char* wrow = (const char*)Wl + lr*4096 + 16*lane;
      float a = 0.f;
      #pragma unroll
      for (int k = 0; k < 4; ++k){
        uint4 wv = *(const uint4*)(wrow + 1024*k);
        a = fdot2(wv.x, hf[k].x, a);
        a = fdot2(wv.y, hf[k].y, a);
        a = fdot2(wv.z, hf[k].z, a);
        a = fdot2(wv.w, hf[k].w, a);
      }
      #pragma unroll
      for (int off = 32; off; off >>= 1) a += __shfl_xor(a, off);
      acc[rr] = a;
    }
    // lanes 0,1: combine and publish their own u32 slot immediately
    if (lane < 2){
      float r  = 1.f/(1.f + expf(-(gr + bhr + acc[0 + lane])));
      float z  = 1.f/(1.f + expf(-(gz + bhz + acc[2 + lane])));
      float ng = tanhf(gn + r*(acc[4 + lane] + bhn));
      float hnew = (1.f - z)*ng + z*hold;
      unsigned pv = ((unsigned)(t + 1) << 16) | (unsigned)f2h(hnew);
      __hip_atomic_store(hbuf + (size_t)(t & 1)*2048 + hbase + 2*w + lane, pv,
                         __ATOMIC_RELAXED, SCOPE_SYS);
      xs[(size_t)t*2048 + hbase + 2*w + lane] = hnew;
      if (t == TS - 1) dout[4 + hbase + 2*w + lane] = hnew;
      hold = hnew;
    }
  }
}

// ---- head ----
__global__ void k_lin1(const float* __restrict__ xs, const float* __restrict__ W,
                       const float* __restrict__ B, float* __restrict__ y1){
  __shared__ float xT[32][36];
  __shared__ float wT[32][36];
  int tid = threadIdx.x;
  int m0 = blockIdx.y*32, n0 = blockIdx.x*32;
  int lm = tid >> 3, lk = (tid & 7)*4;
  int tx = tid & 15, ty = tid >> 4;
  float acc00=0.f, acc01=0.f, acc10=0.f, acc11=0.f;
  for (int k0 = 0; k0 < 2048; k0 += 32){
    float4 xv = make_float4(0.f,0.f,0.f,0.f);
    int tt = m0 + lm;
    if (tt < TS) xv = *(const float4*)(xs + (size_t)tt*2048 + k0 + lk);
    xT[lk+0][lm] = lrelu(xv.x); xT[lk+1][lm] = lrelu(xv.y);
    xT[lk+2][lm] = lrelu(xv.z); xT[lk+3][lm] = lrelu(xv.w);
    float4 wv = make_float4(0.f,0.f,0.f,0.f);
    int jj = n0 + lm;
    if (jj < 400) wv = *(const float4*)(W + (size_t)jj*2048 + k0 + lk);
    wT[lk+0][lm] = wv.x; wT[lk+1][lm] = wv.y; wT[lk+2][lm] = wv.z; wT[lk+3][lm] = wv.w;
    __syncthreads();
    #pragma unroll
    for (int k = 0; k < 32; ++k){
      float2 a = *(const float2*)&xT[k][2*ty];
      float2 b = *(const float2*)&wT[k][2*tx];
      acc00 = fmaf(a.x, b.x, acc00); acc01 = fmaf(a.x, b.y, acc01);
      acc10 = fmaf(a.y, b.x, acc10); acc11 = fmaf(a.y, b.y, acc11);
    }
    __syncthreads();
  }
  int t0 = m0 + 2*ty, j0 = n0 + 2*tx;
  if (t0 < TS){
    if (j0 < 400)   y1[t0*400 + j0]   = acc00 + B[j0];
    if (j0+1 < 400) y1[t0*400 + j0+1] = acc01 + B[j0+1];
  }
  if (t0+1 < TS){
    if (j0 < 400)   y1[(t0+1)*400 + j0]   = acc10 + B[j0];
    if (j0+1 < 400) y1[(t0+1)*400 + j0+1] = acc11 + B[j0+1];
  }
}

__global__ void k_bn3p(const float* __restrict__ y1, float* __restrict__ part){
  __shared__ float red[16];
  float s = 0.f, s2 = 0.f;
  for (int idx = blockIdx.x*256 + threadIdx.x; idx < TS*400; idx += 64*256){
    float v = y1[idx]; s += v; s2 += v*v;
  }
  s  = bred<false>(s, red);
  s2 = bred<false>(s2, red);
  if (threadIdx.x == 0){ part[blockIdx.x] = s; part[64 + blockIdx.x] = s2; }
}

__global__ void k_bn3f(const float* __restrict__ part, float* __restrict__ stats){
  int ln = threadIdx.x;
  float s = part[ln], s2 = part[64 + ln];
  #pragma unroll
  for (int off = 32; off; off >>= 1){ s += __shfl_xor(s, off); s2 += __shfl_xor(s2, off); }
  if (ln == 0){
    float m = s / (float)(TS*400);
    float var = s2 / (float)(TS*400) - m*m;
    stats[0] = m; stats[1] = rsqrtf(var + EPS);
  }
}

__global__ void k_x2(const float* __restrict__ y1, const float* __restrict__ stats,
                     const float* g3, const float* b3, const float* __restrict__ l2w,
                     const float* l2b, float* __restrict__ x2){
  int t = blockIdx.x, ln = threadIdx.x;
  float m = stats[0], iv = stats[1], g = g3[0], b = b3[0];
  float acc = 0.f;
  for (int j = ln; j < 400; j += 64)
    acc = fmaf(lrelu((y1[t*400 + j] - m)*iv*g + b), l2w[j], acc);
  #pragma unroll
  for (int off = 32; off; off >>= 1) acc += __shfl_xor(acc, off);
  if (ln == 0) x2[t] = lrelu(acc + l2b[0]);
}

__global__ void k_head(const float* __restrict__ x2, const float* __restrict__ last,
                       const float* __restrict__ l3w, const float* __restrict__ l3b,
                       const float* __restrict__ l4w, const float* __restrict__ l4b,
                       float* __restrict__ out){
  __shared__ float o1[50];
  int tid = threadIdx.x;
  if (tid < 50){
    float acc = l3b[tid];
    const float* wr = l3w + tid*507;
    for (int i = 0; i < TS; ++i) acc = fmaf(x2[i], wr[i], acc);
    for (int i = 0; i < 4; ++i)  acc = fmaf(last[i], wr[TS + i], acc);
    o1[tid] = lrelu(acc);
  }
  __syncthreads();
  if (tid < 4){
    float acc = l4b[tid];
    const float* wr = l4w + tid*50;
    for (int k = 0; k < 50; ++k) acc = fmaf(o1[k], wr[k], acc);
    out[tid] = acc;
  }
}

// ---- workspace layout (bytes) ----
#define OFF_BN2M    1024u
#define OFF_BN2I    1056u
#define OFF_BN3P    2048u
#define OFF_BN3S    2560u
#define OFF_W2      4096u
#define OFF_SCORE   12288u
#define OFF_X2      20480u
#define OFF_CTX     24576u
#define OFF_CB1     73728u      // cb1 (dead after conv2) is overlaid by hbuf (16KB)
#define OFF_HBUF    73728u
#define OFF_CB2     122880u
#define OFF_CP1     172032u
#define OFF_CB3     196608u
#define OFF_CB4     221184u
#define OFF_SEQ     245760u
#define OFF_GIHAT   274432u
#define OFF_XS      12636160u
#define OFF_Y1      16756736u

extern "C" void kernel_launch(void* const* d_in, const int* in_sizes, int n_in,
                              void* d_out, int out_size, void* d_ws, size_t ws_size,
                              hipStream_t stream){
  const float* last   = (const float*)d_in[0];
  const float* hidden = (const float*)d_in[1];
  const float* enc    = (const float*)d_in[2];
  const float* W1w = (const float*)d_in[3];
  const float* W1b = (const float*)d_in[4];
  const float* W2w = (const float*)d_in[5];
  const float* W2b = (const float*)d_in[6];
  const float* Vw  = (const float*)d_in[7];
  const float* Vb  = (const float*)d_in[8];
  const float* g1  = (const float*)d_in[9];
  const float* b1  = (const float*)d_in[10];
  const float* c1w = (const float*)d_in[11]; const float* c1b = (const float*)d_in[12];
  const float* c2w = (const float*)d_in[13]; const float* c2b = (const float*)d_in[14];
  const float* c3w = (const float*)d_in[15]; const float* c3b = (const float*)d_in[16];
  const float* c4w = (const float*)d_in[17]; const float* c4b = (const float*)d_in[18];
  const float* g2  = (const float*)d_in[19]; const float* b2  = (const float*)d_in[20];
  const float* Wi  = (const float*)d_in[21]; const float* Wh  = (const float*)d_in[22];
  const float* bi  = (const float*)d_in[23]; const float* bhp = (const float*)d_in[24];
  const float* l1w = (const float*)d_in[25]; const float* l1b = (const float*)d_in[26];
  const float* g3  = (const float*)d_in[27]; const float* b3  = (const float*)d_in[28];
  const float* l2w = (const float*)d_in[29]; const float* l2b = (const float*)d_in[30];
  const float* l3w = (const float*)d_in[31]; const float* l3b = (const float*)d_in[32];
  const float* l4w = (const float*)d_in[33]; const float* l4b = (const float*)d_in[34];
  float* out = (float*)d_out;
  char* ws = (char*)d_ws;

  float* bn2m  = (float*)(ws + OFF_BN2M);
  float* bn2i  = (float*)(ws + OFF_BN2I);
  float* bn3p  = (float*)(ws + OFF_BN3P);
  float* bn3s  = (float*)(ws + OFF_BN3S);
  float* w2v   = (float*)(ws + OFF_W2);
  float* score = (float*)(ws + OFF_SCORE);
  float* x2    = (float*)(ws + OFF_X2);
  float* ctx   = (float*)(ws + OFF_CTX);
  float* cb1   = (float*)(ws + OFF_CB1);
  unsigned* hbuf = (unsigned*)(ws + OFF_HBUF);
  float* cb2   = (float*)(ws + OFF_CB2);
  float* cp1   = (float*)(ws + OFF_CP1);
  float* cb3   = (float*)(ws + OFF_CB3);
  float* cb4   = (float*)(ws + OFF_CB4);
  float* seq   = (float*)(ws + OFF_SEQ);
  float* gihat = (float*)(ws + OFF_GIHAT);
  float* xs    = (float*)(ws + OFF_XS);
  float* y1    = (float*)(ws + OFF_Y1);

  k_w2<<<512, 256, 0, stream>>>(W2w, W2b, hidden, w2v);
  k_score<<<512, 256, 0, stream>>>(enc, W1w, W1b, Vw, Vb, w2v, score);
  k_softctx<<<1, 1024, 0, stream>>>(enc, score, g1, b1, ctx);

  k_conv<<<(6*2038 + 255)/256, 256, 0, stream>>>(ctx, 2048, cb1, 2038, c1w, c1b, 11);
  k_conv<<<(6*2028 + 255)/256, 256, 0, stream>>>(cb1, 2038, cb2, 2028, c2w, c2b, 11);
  // cb1 dead from here; clear stale tags in the overlaid hbuf (stream-ordered)
  hipMemsetAsync(hbuf, 0, 2*2048*sizeof(unsigned), stream);
  k_pool<<<(6*1014 + 255)/256, 256, 0, stream>>>(cb2, 2028, cp1, 1014);
  k_conv<<<(6*1010 + 255)/256, 256, 0, stream>>>(cp1, 1014, cb3, 1010, c3w, c3b, 5);
  k_conv<<<(6*1006 + 255)/256, 256, 0, stream>>>(cb3, 1010, cb4, 1006, c4w, c4b, 5);
  k_bn2stats<<<1, 256, 0, stream>>>(cb4, bn2m, bn2i);
  k_seq<<<12, 256, 0, stream>>>(cb4, bn2m, bn2i, g2, b2, seq);
  k_gihat<<<dim3(24, TS), 256, 0, stream>>>(seq, Wi, bi, gihat);

  hipFuncSetAttribute((const void*)k_gru, hipFuncAttributeMaxDynamicSharedMemorySize,
                      (int)GRU_SMEM);
  void* kargs[7] = {(void*)&Wh, (void*)&bhp, (void*)&hidden, (void*)&gihat,
                    (void*)&hbuf, (void*)&xs, (void*)&out};
  hipLaunchCooperativeKernel((const void*)k_gru, dim3(256), dim3(256), kargs,
                             (unsigned)GRU_SMEM, stream);

  k_lin1<<<dim3(13, 16), 256, 0, stream>>>(xs, l1w, l1b, y1);
  k_bn3p<<<64, 256, 0, stream>>>(y1, bn3p);
  k_bn3f<<<1, 64, 0, stream>>>(bn3p, bn3s);
  k_x2<<<TS, 64, 0, stream>>>(y1, bn3s, g3, b3, l2w, l2b, x2);
  k_head<<<1, 64, 0, stream>>>(x2, last, l3w, l3b, l4w, l4b, out);
}

// Round 11
// 2521.075 us; speedup vs baseline: 2.1120x; 1.0210x over previous
//
#include <hip/hip_runtime.h>

#define LEAK 0.2f
#define EPS  1e-5f
#define TS   503
#define SCOPE_SYS __HIP_MEMORY_SCOPE_SYSTEM
typedef unsigned long long ull;

__device__ __forceinline__ float lrelu(float x){ return x >= 0.f ? x : LEAK * x; }

typedef _Float16 half2v __attribute__((ext_vector_type(2)));

__device__ __forceinline__ unsigned short f2h(float x){
  _Float16 h = (_Float16)x;
  return __builtin_bit_cast(unsigned short, h);
}

__device__ __forceinline__ float fdot2(unsigned a, unsigned b, float c){
#if __has_builtin(__builtin_amdgcn_fdot2)
  return __builtin_amdgcn_fdot2(__builtin_bit_cast(half2v, a),
                                __builtin_bit_cast(half2v, b), c, false);
#else
  half2v aa = __builtin_bit_cast(half2v, a);
  half2v bb = __builtin_bit_cast(half2v, b);
  return fmaf((float)aa[1], (float)bb[1], fmaf((float)aa[0], (float)bb[0], c));
#endif
}

// block-wide reduce (sum or max), blockDim multiple of 64
template<bool MAXOP>
__device__ __forceinline__ float bred(float v, float* red){
  #pragma unroll
  for (int off = 32; off; off >>= 1){
    float o = __shfl_xor(v, off);
    v = MAXOP ? fmaxf(v, o) : (v + o);
  }
  int nw = blockDim.x >> 6;
  int wv = threadIdx.x >> 6, ln = threadIdx.x & 63;
  __syncthreads();
  if (ln == 0) red[wv] = v;
  __syncthreads();
  if (wv == 0){
    float x = (ln < nw) ? red[ln] : (MAXOP ? -3.402823466e38f : 0.f);
    #pragma unroll
    for (int off = 8; off; off >>= 1){
      float o = __shfl_xor(x, off);
      x = MAXOP ? fmaxf(x, o) : (x + o);
    }
    if (ln == 0) red[0] = x;
  }
  __syncthreads();
  return red[0];
}

// ---- attention ----
__global__ void k_w2(const float* __restrict__ W2w, const float* __restrict__ W2b,
                     const float* __restrict__ hidden, float* __restrict__ w2v){
  int wave = threadIdx.x >> 6, lane = threadIdx.x & 63;
  int row = blockIdx.x*4 + wave;
  const float* wr = W2w + (size_t)row*2048;
  float acc = 0.f;
  #pragma unroll
  for (int k = 0; k < 8; ++k){
    int base = 4*lane + 256*k;
    float4 w = *(const float4*)(wr + base);
    float4 h = *(const float4*)(hidden + base);
    acc = fmaf(w.x,h.x, fmaf(w.y,h.y, fmaf(w.z,h.z, fmaf(w.w,h.w, acc))));
  }
  #pragma unroll
  for (int off = 32; off; off >>= 1) acc += __shfl_xor(acc, off);
  if (lane == 0) w2v[row] = lrelu(acc + W2b[row]);
}

__global__ void k_score(const float* __restrict__ enc, const float* __restrict__ W1w,
                        const float* __restrict__ W1b, const float* __restrict__ Vw,
                        const float* __restrict__ Vb, const float* __restrict__ w2v,
                        float* __restrict__ score){
  __shared__ float sW1[2048*6];
  int tid = threadIdx.x;
  for (int idx = tid; idx < 2048*6; idx += 256) sW1[idx] = W1w[idx];
  __syncthreads();
  int wave = tid >> 6, lane = tid & 63;
  int i = blockIdx.x*4 + wave;
  float e0 = enc[(size_t)i*6+0], e1 = enc[(size_t)i*6+1], e2 = enc[(size_t)i*6+2];
  float e3 = enc[(size_t)i*6+3], e4 = enc[(size_t)i*6+4], e5 = enc[(size_t)i*6+5];
  float acc = 0.f;
  for (int jj = 0; jj < 32; ++jj){
    int j = lane + 64*jj;
    const float* wr = sW1 + j*6;
    float a = fmaf(e0,wr[0], fmaf(e1,wr[1], fmaf(e2,wr[2],
              fmaf(e3,wr[3], fmaf(e4,wr[4], fmaf(e5,wr[5], W1b[j]))))));
    acc = fmaf(lrelu(a), Vw[j], acc);
  }
  #pragma unroll
  for (int off = 32; off; off >>= 1) acc += __shfl_xor(acc, off);
  if (lane == 0) score[i] = acc + w2v[i]*Vw[2048] + Vb[0];
}

__global__ void k_softctx(const float* __restrict__ enc, const float* __restrict__ score,
                          const float* g1, const float* b1, float* __restrict__ ctx){
  __shared__ float red[16];
  int tid = threadIdx.x;
  float s0 = score[tid], s1 = score[tid + 1024];
  float mean = bred<false>(s0 + s1, red) * (1.f/2048.f);
  float d0 = s0 - mean, d1 = s1 - mean;
  float var = bred<false>(d0*d0 + d1*d1, red) * (1.f/2048.f);
  float iv = rsqrtf(var + EPS);
  float g = g1[0], b = b1[0];
  float v0 = lrelu(d0*iv*g + b), v1 = lrelu(d1*iv*g + b);
  float mx = bred<true>(fmaxf(v0, v1), red);
  float e0 = expf(v0 - mx), e1 = expf(v1 - mx);
  float se = bred<false>(e0 + e1, red);
  float w0 = e0/se, w1 = e1/se;
  #pragma unroll
  for (int c = 0; c < 6; ++c){
    ctx[c*2048 + tid]        = enc[(size_t)tid*6 + c] * w0;
    ctx[c*2048 + tid + 1024] = enc[(size_t)(tid+1024)*6 + c] * w1;
  }
}

// ---- CNN ----
__global__ void k_conv(const float* __restrict__ in, int Lin,
                       float* __restrict__ out, int Lout,
                       const float* __restrict__ w, const float* __restrict__ b, int K){
  int idx = blockIdx.x*256 + threadIdx.x;
  if (idx >= 6*Lout) return;
  int o = idx / Lout, x = idx - o*Lout;
  float acc = b[o];
  for (int i = 0; i < 6; ++i){
    const float* ir = in + i*Lin + x;
    const float* wr = w + (o*6 + i)*K;
    for (int k = 0; k < K; ++k) acc = fmaf(ir[k], wr[k], acc);
  }
  out[o*Lout + x] = lrelu(acc);
}

__global__ void k_pool(const float* __restrict__ in, int Lin, float* __restrict__ out, int Lout){
  int idx = blockIdx.x*256 + threadIdx.x;
  if (idx >= 6*Lout) return;
  int o = idx / Lout, x = idx - o*Lout;
  out[idx] = fmaxf(in[o*Lin + 2*x], in[o*Lin + 2*x + 1]);
}

__global__ void k_bn2stats(const float* __restrict__ in, float* m6, float* i6){
  __shared__ float red[16];
  for (int c = 0; c < 6; ++c){
    float s = 0.f, s2 = 0.f;
    for (int i = threadIdx.x; i < 1006; i += 256){
      float v = in[c*1006 + i]; s += v; s2 += v*v;
    }
    s  = bred<false>(s, red);
    s2 = bred<false>(s2, red);
    if (threadIdx.x == 0){
      float m = s / 1006.f;
      float var = s2 / 1006.f - m*m;
      m6[c] = m; i6[c] = rsqrtf(var + EPS);
    }
  }
}

__global__ void k_seq(const float* __restrict__ cb4, const float* m6, const float* i6,
                      const float* g2, const float* b2, float* __restrict__ seq){
  int idx = blockIdx.x*256 + threadIdx.x;
  if (idx >= TS*6) return;
  int c = idx % 6, t = idx / 6;
  float m = m6[c], iv = i6[c], g = g2[c], b = b2[c];
  float v0 = (cb4[c*1006 + 2*t]     - m)*iv*g + b;
  float v1 = (cb4[c*1006 + 2*t + 1] - m)*iv*g + b;
  seq[idx] = fmaxf(v0, v1);
}

__global__ void k_gihat(const float* __restrict__ seq, const float* __restrict__ Wi,
                        const float* __restrict__ bi, float* __restrict__ gihat){
  int row = blockIdx.x*256 + threadIdx.x;   // < 6144
  int t = blockIdx.y;
  const float* s = seq + t*6;
  const float* w = Wi + (size_t)row*6;
  float v = fmaf(s[0],w[0], fmaf(s[1],w[1], fmaf(s[2],w[2],
            fmaf(s[3],w[3], fmaf(s[4],w[4], fmaf(s[5],w[5], bi[row]))))));
  gihat[(size_t)t*6144 + row] = v;
}

// ---- GRU: 256 WGs, LDS f16 Wh; tagged u32 publish, CHANNEL-SCATTERED slots --
// Protocol = r5/r10 family (the measured optimum: system-scope relaxed tagged
// values, detect==read, one RT, sleep(1) between sweeps). ONE change: slot s
// lives on its own 256B-aligned granule (byte s*256 + parity*64) instead of
// packed into 128 consecutive lines. Spreads the chip-wide poll sweep across
// ~4096 lines on all MALL slices/channels -- tests the hot-line service-queue
// hypothesis for the ~11k-cycle step cadence. Buffer = 524KB, overlaid on y1
// (dead during k_gru; k_lin1 rewrites it afterwards), memset per launch.
// WAR over the 2-parity buffer: a WG publishes step t only after its post-poll
// barrier (all its reads of t-1 done); publishing t+2 (same parity) implies
// every WG finished reading parity t&1.
#define GRU_SMEM (24*2048*2 + 1024*4)

__global__ void __launch_bounds__(256, 1)
k_gru(const float* __restrict__ Wh, const float* __restrict__ bh,
      const float* __restrict__ hidden, const float* __restrict__ gihat,
      unsigned* hbuf, float* __restrict__ xs, float* __restrict__ dout){
  extern __shared__ char smem[];
  ushort* Wl    = (ushort*)smem;                 // [24][2048] f16
  unsigned* h2  = (unsigned*)(smem + 24*2048*2); // [1024] f16x2 pairs
  const int tid = threadIdx.x, wg = blockIdx.x;
  const int lane = tid & 63, w = tid >> 6;
  const int hbase = wg << 3;

  // stage weights: wave w's local rows 6w+k, k=0..5 -> gate k>>1, output k&1
  for (int idx = tid; idx < 24*2048; idx += 256){
    int lr = idx >> 11, col = idx & 2047;
    int wv = lr/6, k = lr - 6*wv, gate = k >> 1, o = k & 1;
    int grow = (gate << 11) + hbase + 2*wv + o;
    Wl[idx] = f2h(Wh[(size_t)grow*2048 + col]);
  }
  float bhr = 0.f, bhz = 0.f, bhn = 0.f, hold = 0.f;
  if (lane < 2){
    int o = hbase + 2*w + lane;
    bhr = bh[o]; bhz = bh[2048 + o]; bhn = bh[4096 + o];
    hold = hidden[o];
  }
  __syncthreads();

  for (int t = 0; t < TS; ++t){
    // per-step input-gate biases for this wave's 2 outputs (hide under poll)
    float gr = 0.f, gz = 0.f, gn = 0.f;
    if (lane < 2){
      const float* gp = gihat + (size_t)t*6144 + hbase + 2*w + lane;
      gr = gp[0]; gz = gp[2048]; gn = gp[4096];
    }
    // acquire h[t-1]: thread tid owns slots 8*tid..8*tid+7 (h[8t..8t+8)),
    // slot s at u32 offset s*64 + parity*16 (256B granule, 64B parity line)
    if (t == 0){
      const float4* hp = (const float4*)(hidden + 8*tid);
      float4 a = hp[0], b = hp[1];
      unsigned p0 = (unsigned)f2h(a.x) | ((unsigned)f2h(a.y) << 16);
      unsigned p1 = (unsigned)f2h(a.z) | ((unsigned)f2h(a.w) << 16);
      unsigned p2 = (unsigned)f2h(b.x) | ((unsigned)f2h(b.y) << 16);
      unsigned p3 = (unsigned)f2h(b.z) | ((unsigned)f2h(b.w) << 16);
      *(uint4*)(h2 + 4*tid) = make_uint4(p0, p1, p2, p3);
    } else {
      const unsigned* src = hbuf + (size_t)(8*tid)*64 + (size_t)((t - 1) & 1)*16;
      const unsigned expect = (unsigned)t;   // tag16 of step t-1's publish
      unsigned v[8];
      unsigned done = 0;
      for (;;){
        #pragma unroll
        for (int j = 0; j < 8; ++j)
          if (!((done >> j) & 1u))
            v[j] = __hip_atomic_load(src + (size_t)j*64, __ATOMIC_RELAXED, SCOPE_SYS);
        unsigned nd = done;
        #pragma unroll
        for (int j = 0; j < 8; ++j)
          if (!((done >> j) & 1u) && (v[j] >> 16) == expect) nd |= (1u << j);
        if (nd == 255u) break;
        done = nd;
        __builtin_amdgcn_s_sleep(1);
      }
      unsigned p0 = (v[0] & 0xffffu) | (v[1] << 16);
      unsigned p1 = (v[2] & 0xffffu) | (v[3] << 16);
      unsigned p2 = (v[4] & 0xffffu) | (v[5] << 16);
      unsigned p3 = (v[6] & 0xffffu) | (v[7] << 16);
      *(uint4*)(h2 + 4*tid) = make_uint4(p0, p1, p2, p3);
    }
    __syncthreads();

    // per-lane h fragment: 4 x b128 = 32 h values as 16 f16-pairs
    uint4 hf[4];
    #pragma unroll
    for (int k = 0; k < 4; ++k)
      hf[k] = *(const uint4*)((const char*)h2 + 16*lane + 1024*k);
    // 6 dot rows; full butterfly so every lane ends with all 6 sums
    float acc[6];
    #pragma unroll
    for (int rr = 0; rr < 6; ++rr){
      int lr = 6*w + rr;
      const char* wrow = (const char*)Wl + lr*4096 + 16*lane;
      float a = 0.f;
      #pragma unroll
      for (int k = 0; k < 4; ++k){
        uint4 wv = *(const uint4*)(wrow + 1024*k);
        a = fdot2(wv.x, hf[k].x, a);
        a = fdot2(wv.y, hf[k].y, a);
        a = fdot2(wv.z, hf[k].z, a);
        a = fdot2(wv.w, hf[k].w, a);
      }
      #pragma unroll
      for (int off = 32; off; off >>= 1) a += __shfl_xor(a, off);
      acc[rr] = a;
    }
    // lanes 0,1: combine and publish their own u32 slot immediately
    if (lane < 2){
      float r  = 1.f/(1.f + expf(-(gr + bhr + acc[0 + lane])));
      float z  = 1.f/(1.f + expf(-(gz + bhz + acc[2 + lane])));
      float ng = tanhf(gn + r*(acc[4 + lane] + bhn));
      float hnew = (1.f - z)*ng + z*hold;
      unsigned pv = ((unsigned)(t + 1) << 16) | (unsigned)f2h(hnew);
      int slot = hbase + 2*w + lane;
      __hip_atomic_store(hbuf + (size_t)slot*64 + (size_t)(t & 1)*16, pv,
                         __ATOMIC_RELAXED, SCOPE_SYS);
      xs[(size_t)t*2048 + slot] = hnew;
      if (t == TS - 1) dout[4 + slot] = hnew;
      hold = hnew;
    }
  }
}

// ---- head ----
__global__ void k_lin1(const float* __restrict__ xs, const float* __restrict__ W,
                       const float* __restrict__ B, float* __restrict__ y1){
  __shared__ float xT[32][36];
  __shared__ float wT[32][36];
  int tid = threadIdx.x;
  int m0 = blockIdx.y*32, n0 = blockIdx.x*32;
  int lm = tid >> 3, lk = (tid & 7)*4;
  int tx = tid & 15, ty = tid >> 4;
  float acc00=0.f, acc01=0.f, acc10=0.f, acc11=0.f;
  for (int k0 = 0; k0 < 2048; k0 += 32){
    float4 xv = make_float4(0.f,0.f,0.f,0.f);
    int tt = m0 + lm;
    if (tt < TS) xv = *(const float4*)(xs + (size_t)tt*2048 + k0 + lk);
    xT[lk+0][lm] = lrelu(xv.x); xT[lk+1][lm] = lrelu(xv.y);
    xT[lk+2][lm] = lrelu(xv.z); xT[lk+3][lm] = lrelu(xv.w);
    float4 wv = make_float4(0.f,0.f,0.f,0.f);
    int jj = n0 + lm;
    if (jj < 400) wv = *(const float4*)(W + (size_t)jj*2048 + k0 + lk);
    wT[lk+0][lm] = wv.x; wT[lk+1][lm] = wv.y; wT[lk+2][lm] = wv.z; wT[lk+3][lm] = wv.w;
    __syncthreads();
    #pragma unroll
    for (int k = 0; k < 32; ++k){
      float2 a = *(const float2*)&xT[k][2*ty];
      float2 b = *(const float2*)&wT[k][2*tx];
      acc00 = fmaf(a.x, b.x, acc00); acc01 = fmaf(a.x, b.y, acc01);
      acc10 = fmaf(a.y, b.x, acc10); acc11 = fmaf(a.y, b.y, acc11);
    }
    __syncthreads();
  }
  int t0 = m0 + 2*ty, j0 = n0 + 2*tx;
  if (t0 < TS){
    if (j0 < 400)   y1[t0*400 + j0]   = acc00 + B[j0];
    if (j0+1 < 400) y1[t0*400 + j0+1] = acc01 + B[j0+1];
  }
  if (t0+1 < TS){
    if (j0 < 400)   y1[(t0+1)*400 + j0]   = acc10 + B[j0];
    if (j0+1 < 400) y1[(t0+1)*400 + j0+1] = acc11 + B[j0+1];
  }
}

__global__ void k_bn3p(const float* __restrict__ y1, float* __restrict__ part){
  __shared__ float red[16];
  float s = 0.f, s2 = 0.f;
  for (int idx = blockIdx.x*256 + threadIdx.x; idx < TS*400; idx += 64*256){
    float v = y1[idx]; s += v; s2 += v*v;
  }
  s  = bred<false>(s, red);
  s2 = bred<false>(s2, red);
  if (threadIdx.x == 0){ part[blockIdx.x] = s; part[64 + blockIdx.x] = s2; }
}

__global__ void k_bn3f(const float* __restrict__ part, float* __restrict__ stats){
  int ln = threadIdx.x;
  float s = part[ln], s2 = part[64 + ln];
  #pragma unroll
  for (int off = 32; off; off >>= 1){ s += __shfl_xor(s, off); s2 += __shfl_xor(s2, off); }
  if (ln == 0){
    float m = s / (float)(TS*400);
    float var = s2 / (float)(TS*400) - m*m;
    stats[0] = m; stats[1] = rsqrtf(var + EPS);
  }
}

__global__ void k_x2(const float* __restrict__ y1, const float* __restrict__ stats,
                     const float* g3, const float* b3, const float* __restrict__ l2w,
                     const float* l2b, float* __restrict__ x2){
  int t = blockIdx.x, ln = threadIdx.x;
  float m = stats[0], iv = stats[1], g = g3[0], b = b3[0];
  float acc = 0.f;
  for (int j = ln; j < 400; j += 64)
    acc = fmaf(lrelu((y1[t*400 + j] - m)*iv*g + b), l2w[j], acc);
  #pragma unroll
  for (int off = 32; off; off >>= 1) acc += __shfl_xor(acc, off);
  if (ln == 0) x2[t] = lrelu(acc + l2b[0]);
}

__global__ void k_head(const float* __restrict__ x2, const float* __restrict__ last,
                       const float* __restrict__ l3w, const float* __restrict__ l3b,
                       const float* __restrict__ l4w, const float* __restrict__ l4b,
                       float* __restrict__ out){
  __shared__ float o1[50];
  int tid = threadIdx.x;
  if (tid < 50){
    float acc = l3b[tid];
    const float* wr = l3w + tid*507;
    for (int i = 0; i < TS; ++i) acc = fmaf(x2[i], wr[i], acc);
    for (int i = 0; i < 4; ++i)  acc = fmaf(last[i], wr[TS + i], acc);
    o1[tid] = lrelu(acc);
  }
  __syncthreads();
  if (tid < 4){
    float acc = l4b[tid];
    const float* wr = l4w + tid*50;
    for (int k = 0; k < 50; ++k) acc = fmaf(o1[k], wr[k], acc);
    out[tid] = acc;
  }
}

// ---- workspace layout (bytes) ----
#define OFF_BN2M    1024u
#define OFF_BN2I    1056u
#define OFF_BN3P    2048u
#define OFF_BN3S    2560u
#define OFF_W2      4096u
#define OFF_SCORE   12288u
#define OFF_X2      20480u
#define OFF_CTX     24576u
#define OFF_CB1     73728u
#define OFF_CB2     122880u
#define OFF_CP1     172032u
#define OFF_CB3     196608u
#define OFF_CB4     221184u
#define OFF_SEQ     245760u
#define OFF_GIHAT   274432u
#define OFF_XS      12636160u
#define OFF_Y1      16756736u
// hbuf: 2048 slots x 256B granule = 524288B, overlaid on y1 (dead during
// k_gru; k_lin1 rewrites y1 afterwards). memset per launch before k_gru.
#define OFF_HBUF    16756736u
#define HBUF_BYTES  524288u

extern "C" void kernel_launch(void* const* d_in, const int* in_sizes, int n_in,
                              void* d_out, int out_size, void* d_ws, size_t ws_size,
                              hipStream_t stream){
  const float* last   = (const float*)d_in[0];
  const float* hidden = (const float*)d_in[1];
  const float* enc    = (const float*)d_in[2];
  const float* W1w = (const float*)d_in[3];
  const float* W1b = (const float*)d_in[4];
  const float* W2w = (const float*)d_in[5];
  const float* W2b = (const float*)d_in[6];
  const float* Vw  = (const float*)d_in[7];
  const float* Vb  = (const float*)d_in[8];
  const float* g1  = (const float*)d_in[9];
  const float* b1  = (const float*)d_in[10];
  const float* c1w = (const float*)d_in[11]; const float* c1b = (const float*)d_in[12];
  const float* c2w = (const float*)d_in[13]; const float* c2b = (const float*)d_in[14];
  const float* c3w = (const float*)d_in[15]; const float* c3b = (const float*)d_in[16];
  const float* c4w = (const float*)d_in[17]; const float* c4b = (const float*)d_in[18];
  const float* g2  = (const float*)d_in[19]; const float* b2  = (const float*)d_in[20];
  const float* Wi  = (const float*)d_in[21]; const float* Wh  = (const float*)d_in[22];
  const float* bi  = (const float*)d_in[23]; const float* bhp = (const float*)d_in[24];
  const float* l1w = (const float*)d_in[25]; const float* l1b = (const float*)d_in[26];
  const float* g3  = (const float*)d_in[27]; const float* b3  = (const float*)d_in[28];
  const float* l2w = (const float*)d_in[29]; const float* l2b = (const float*)d_in[30];
  const float* l3w = (const float*)d_in[31]; const float* l3b = (const float*)d_in[32];
  const float* l4w = (const float*)d_in[33]; const float* l4b = (const float*)d_in[34];
  float* out = (float*)d_out;
  char* ws = (char*)d_ws;

  float* bn2m  = (float*)(ws + OFF_BN2M);
  float* bn2i  = (float*)(ws + OFF_BN2I);
  float* bn3p  = (float*)(ws + OFF_BN3P);
  float* bn3s  = (float*)(ws + OFF_BN3S);
  float* w2v   = (float*)(ws + OFF_W2);
  float* score = (float*)(ws + OFF_SCORE);
  float* x2    = (float*)(ws + OFF_X2);
  float* ctx   = (float*)(ws + OFF_CTX);
  float* cb1   = (float*)(ws + OFF_CB1);
  unsigned* hbuf = (unsigned*)(ws + OFF_HBUF);
  float* cb2   = (float*)(ws + OFF_CB2);
  float* cp1   = (float*)(ws + OFF_CP1);
  float* cb3   = (float*)(ws + OFF_CB3);
  float* cb4   = (float*)(ws + OFF_CB4);
  float* seq   = (float*)(ws + OFF_SEQ);
  float* gihat = (float*)(ws + OFF_GIHAT);
  float* xs    = (float*)(ws + OFF_XS);
  float* y1    = (float*)(ws + OFF_Y1);

  k_w2<<<512, 256, 0, stream>>>(W2w, W2b, hidden, w2v);
  k_score<<<512, 256, 0, stream>>>(enc, W1w, W1b, Vw, Vb, w2v, score);
  k_softctx<<<1, 1024, 0, stream>>>(enc, score, g1, b1, ctx);

  k_conv<<<(6*2038 + 255)/256, 256, 0, stream>>>(ctx, 2048, cb1, 2038, c1w, c1b, 11);
  k_conv<<<(6*2028 + 255)/256, 256, 0, stream>>>(cb1, 2038, cb2, 2028, c2w, c2b, 11);
  // clear stale tags in the y1-overlaid hbuf (y1 dead until k_lin1)
  hipMemsetAsync(hbuf, 0, HBUF_BYTES, stream);
  k_pool<<<(6*1014 + 255)/256, 256, 0, stream>>>(cb2, 2028, cp1, 1014);
  k_conv<<<(6*1010 + 255)/256, 256, 0, stream>>>(cp1, 1014, cb3, 1010, c3w, c3b, 5);
  k_conv<<<(6*1006 + 255)/256, 256, 0, stream>>>(cb3, 1010, cb4, 1006, c4w, c4b, 5);
  k_bn2stats<<<1, 256, 0, stream>>>(cb4, bn2m, bn2i);
  k_seq<<<12, 256, 0, stream>>>(cb4, bn2m, bn2i, g2, b2, seq);
  k_gihat<<<dim3(24, TS), 256, 0, stream>>>(seq, Wi, bi, gihat);

  hipFuncSetAttribute((const void*)k_gru, hipFuncAttributeMaxDynamicSharedMemorySize,
                      (int)GRU_SMEM);
  void* kargs[7] = {(void*)&Wh, (void*)&bhp, (void*)&hidden, (void*)&gihat,
                    (void*)&hbuf, (void*)&xs, (void*)&out};
  hipLaunchCooperativeKernel((const void*)k_gru, dim3(256), dim3(256), kargs,
                             (unsigned)GRU_SMEM, stream);

  k_lin1<<<dim3(13, 16), 256, 0, stream>>>(xs, l1w, l1b, y1);
  k_bn3p<<<64, 256, 0, stream>>>(y1, bn3p);
  k_bn3f<<<1, 64, 0, stream>>>(bn3p, bn3s);
  k_x2<<<TS, 64, 0, stream>>>(y1, bn3s, g3, b3, l2w, l2b, x2);
  k_head<<<1, 64, 0, stream>>>(x2, last, l3w, l3b, l4w, l4b, out);
}

// Round 12
// 2059.176 us; speedup vs baseline: 2.5857x; 1.2243x over previous
//
#include <hip/hip_runtime.h>

#define LEAK 0.2f
#define EPS  1e-5f
#define TS   503
#define SCOPE_SYS __HIP_MEMORY_SCOPE_SYSTEM
typedef unsigned long long ull;

__device__ __forceinline__ float lrelu(float x){ return x >= 0.f ? x : LEAK * x; }

typedef _Float16 half2v __attribute__((ext_vector_type(2)));

__device__ __forceinline__ unsigned short f2h(float x){
  _Float16 h = (_Float16)x;
  return __builtin_bit_cast(unsigned short, h);
}

__device__ __forceinline__ float fdot2(unsigned a, unsigned b, float c){
#if __has_builtin(__builtin_amdgcn_fdot2)
  return __builtin_amdgcn_fdot2(__builtin_bit_cast(half2v, a),
                                __builtin_bit_cast(half2v, b), c, false);
#else
  half2v aa = __builtin_bit_cast(half2v, a);
  half2v bb = __builtin_bit_cast(half2v, b);
  return fmaf((float)aa[1], (float)bb[1], fmaf((float)aa[0], (float)bb[0], c));
#endif
}

// block-wide reduce (sum or max), blockDim multiple of 64
template<bool MAXOP>
__device__ __forceinline__ float bred(float v, float* red){
  #pragma unroll
  for (int off = 32; off; off >>= 1){
    float o = __shfl_xor(v, off);
    v = MAXOP ? fmaxf(v, o) : (v + o);
  }
  int nw = blockDim.x >> 6;
  int wv = threadIdx.x >> 6, ln = threadIdx.x & 63;
  __syncthreads();
  if (ln == 0) red[wv] = v;
  __syncthreads();
  if (wv == 0){
    float x = (ln < nw) ? red[ln] : (MAXOP ? -3.402823466e38f : 0.f);
    #pragma unroll
    for (int off = 8; off; off >>= 1){
      float o = __shfl_xor(x, off);
      x = MAXOP ? fmaxf(x, o) : (x + o);
    }
    if (ln == 0) red[0] = x;
  }
  __syncthreads();
  return red[0];
}

// ---- attention ----
__global__ void k_w2(const float* __restrict__ W2w, const float* __restrict__ W2b,
                     const float* __restrict__ hidden, float* __restrict__ w2v){
  int wave = threadIdx.x >> 6, lane = threadIdx.x & 63;
  int row = blockIdx.x*4 + wave;
  const float* wr = W2w + (size_t)row*2048;
  float acc = 0.f;
  #pragma unroll
  for (int k = 0; k < 8; ++k){
    int base = 4*lane + 256*k;
    float4 w = *(const float4*)(wr + base);
    float4 h = *(const float4*)(hidden + base);
    acc = fmaf(w.x,h.x, fmaf(w.y,h.y, fmaf(w.z,h.z, fmaf(w.w,h.w, acc))));
  }
  #pragma unroll
  for (int off = 32; off; off >>= 1) acc += __shfl_xor(acc, off);
  if (lane == 0) w2v[row] = lrelu(acc + W2b[row]);
}

__global__ void k_score(const float* __restrict__ enc, const float* __restrict__ W1w,
                        const float* __restrict__ W1b, const float* __restrict__ Vw,
                        const float* __restrict__ Vb, const float* __restrict__ w2v,
                        float* __restrict__ score){
  __shared__ float sW1[2048*6];
  int tid = threadIdx.x;
  for (int idx = tid; idx < 2048*6; idx += 256) sW1[idx] = W1w[idx];
  __syncthreads();
  int wave = tid >> 6, lane = tid & 63;
  int i = blockIdx.x*4 + wave;
  float e0 = enc[(size_t)i*6+0], e1 = enc[(size_t)i*6+1], e2 = enc[(size_t)i*6+2];
  float e3 = enc[(size_t)i*6+3], e4 = enc[(size_t)i*6+4], e5 = enc[(size_t)i*6+5];
  float acc = 0.f;
  for (int jj = 0; jj < 32; ++jj){
    int j = lane + 64*jj;
    const float* wr = sW1 + j*6;
    float a = fmaf(e0,wr[0], fmaf(e1,wr[1], fmaf(e2,wr[2],
              fmaf(e3,wr[3], fmaf(e4,wr[4], fmaf(e5,wr[5], W1b[j]))))));
    acc = fmaf(lrelu(a), Vw[j], acc);
  }
  #pragma unroll
  for (int off = 32; off; off >>= 1) acc += __shfl_xor(acc, off);
  if (lane == 0) score[i] = acc + w2v[i]*Vw[2048] + Vb[0];
}

__global__ void k_softctx(const float* __restrict__ enc, const float* __restrict__ score,
                          const float* g1, const float* b1, float* __restrict__ ctx){
  __shared__ float red[16];
  int tid = threadIdx.x;
  float s0 = score[tid], s1 = score[tid + 1024];
  float mean = bred<false>(s0 + s1, red) * (1.f/2048.f);
  float d0 = s0 - mean, d1 = s1 - mean;
  float var = bred<false>(d0*d0 + d1*d1, red) * (1.f/2048.f);
  float iv = rsqrtf(var + EPS);
  float g = g1[0], b = b1[0];
  float v0 = lrelu(d0*iv*g + b), v1 = lrelu(d1*iv*g + b);
  float mx = bred<true>(fmaxf(v0, v1), red);
  float e0 = expf(v0 - mx), e1 = expf(v1 - mx);
  float se = bred<false>(e0 + e1, red);
  float w0 = e0/se, w1 = e1/se;
  #pragma unroll
  for (int c = 0; c < 6; ++c){
    ctx[c*2048 + tid]        = enc[(size_t)tid*6 + c] * w0;
    ctx[c*2048 + tid + 1024] = enc[(size_t)(tid+1024)*6 + c] * w1;
  }
}

// ---- CNN ----
__global__ void k_conv(const float* __restrict__ in, int Lin,
                       float* __restrict__ out, int Lout,
                       const float* __restrict__ w, const float* __restrict__ b, int K){
  int idx = blockIdx.x*256 + threadIdx.x;
  if (idx >= 6*Lout) return;
  int o = idx / Lout, x = idx - o*Lout;
  float acc = b[o];
  for (int i = 0; i < 6; ++i){
    const float* ir = in + i*Lin + x;
    const float* wr = w + (o*6 + i)*K;
    for (int k = 0; k < K; ++k) acc = fmaf(ir[k], wr[k], acc);
  }
  out[o*Lout + x] = lrelu(acc);
}

__global__ void k_pool(const float* __restrict__ in, int Lin, float* __restrict__ out, int Lout){
  int idx = blockIdx.x*256 + threadIdx.x;
  if (idx >= 6*Lout) return;
  int o = idx / Lout, x = idx - o*Lout;
  out[idx] = fmaxf(in[o*Lin + 2*x], in[o*Lin + 2*x + 1]);
}

__global__ void k_bn2stats(const float* __restrict__ in, float* m6, float* i6){
  __shared__ float red[16];
  for (int c = 0; c < 6; ++c){
    float s = 0.f, s2 = 0.f;
    for (int i = threadIdx.x; i < 1006; i += 256){
      float v = in[c*1006 + i]; s += v; s2 += v*v;
    }
    s  = bred<false>(s, red);
    s2 = bred<false>(s2, red);
    if (threadIdx.x == 0){
      float m = s / 1006.f;
      float var = s2 / 1006.f - m*m;
      m6[c] = m; i6[c] = rsqrtf(var + EPS);
    }
  }
}

__global__ void k_seq(const float* __restrict__ cb4, const float* m6, const float* i6,
                      const float* g2, const float* b2, float* __restrict__ seq){
  int idx = blockIdx.x*256 + threadIdx.x;
  if (idx >= TS*6) return;
  int c = idx % 6, t = idx / 6;
  float m = m6[c], iv = i6[c], g = g2[c], b = b2[c];
  float v0 = (cb4[c*1006 + 2*t]     - m)*iv*g + b;
  float v1 = (cb4[c*1006 + 2*t + 1] - m)*iv*g + b;
  seq[idx] = fmaxf(v0, v1);
}

__global__ void k_gihat(const float* __restrict__ seq, const float* __restrict__ Wi,
                        const float* __restrict__ bi, float* __restrict__ gihat){
  int row = blockIdx.x*256 + threadIdx.x;   // < 6144
  int t = blockIdx.y;
  const float* s = seq + t*6;
  const float* w = Wi + (size_t)row*6;
  float v = fmaf(s[0],w[0], fmaf(s[1],w[1], fmaf(s[2],w[2],
            fmaf(s[3],w[3], fmaf(s[4],w[4], fmaf(s[5],w[5], bi[row]))))));
  gihat[(size_t)t*6144 + row] = v;
}

// ---- GRU: 256 co-resident WGs, LDS f16 Wh, tagged-value sync (r5 = measured
// optimum of the protocol family; r6-r11 scanned every structural/tuning
// alternative and all regressed). Each published slot is u64 {tag=t+1 | f16x2}
// stored with a SYSTEM-scope relaxed atomic (MALL coherence point, no cache
// maintenance). Consumer thread tid polls its 4 slots until tags match:
// detect==read, one RT, s_sleep(1) cadence (the measured optimum). Only change
// vs r5: gate combine uses fast-math __expf/__fdividef (serial-path shave;
// error ~1e-6 << f16 transport error). WAR over the 2-parity buffer: a WG
// publishes step t only after its post-poll barrier; publishing t+2 (same
// parity) implies every WG finished reading parity t&1. Stale tags cleared by
// a 16KB memset per launch.
#define GRU_SMEM (24*2048*2 + 1024*4)

__global__ void __launch_bounds__(256, 1)
k_gru(const float* __restrict__ Wh, const float* __restrict__ bh,
      const float* __restrict__ hidden, const float* __restrict__ gihat,
      ull* hbuf, float* __restrict__ xs, float* __restrict__ dout){
  extern __shared__ char smem[];
  ushort* Wl    = (ushort*)smem;                 // [24][2048] f16
  unsigned* h2  = (unsigned*)(smem + 24*2048*2); // [1024] f16x2 pairs
  const int tid = threadIdx.x, wg = blockIdx.x;
  const int lane = tid & 63, w = tid >> 6;
  const int hbase = wg << 3;

  // stage weights: wave w's local rows 6w+k, k=0..5 -> gate k>>1, output k&1
  for (int idx = tid; idx < 24*2048; idx += 256){
    int lr = idx >> 11, col = idx & 2047;
    int wv = lr/6, k = lr - 6*wv, gate = k >> 1, o = k & 1;
    int grow = (gate << 11) + hbase + 2*wv + o;
    Wl[idx] = f2h(Wh[(size_t)grow*2048 + col]);
  }
  float bhr = 0.f, bhz = 0.f, bhn = 0.f, hold = 0.f;
  if (lane < 2){
    int o = hbase + 2*w + lane;
    bhr = bh[o]; bhz = bh[2048 + o]; bhn = bh[4096 + o];
    hold = hidden[o];
  }
  __syncthreads();

  for (int t = 0; t < TS; ++t){
    // per-step input-gate biases for this wave's 2 outputs (hide under poll)
    float gr = 0.f, gz = 0.f, gn = 0.f;
    if (lane < 2){
      const float* gp = gihat + (size_t)t*6144 + hbase + 2*w + lane;
      gr = gp[0]; gz = gp[2048]; gn = gp[4096];
    }
    // acquire h[t-1]: thread tid owns slots 4*tid..4*tid+3 (h[8t..8t+8))
    if (t == 0){
      const float4* hp = (const float4*)(hidden + 8*tid);
      float4 a = hp[0], b = hp[1];
      unsigned p0 = (unsigned)f2h(a.x) | ((unsigned)f2h(a.y) << 16);
      unsigned p1 = (unsigned)f2h(a.z) | ((unsigned)f2h(a.w) << 16);
      unsigned p2 = (unsigned)f2h(b.x) | ((unsigned)f2h(b.y) << 16);
      unsigned p3 = (unsigned)f2h(b.z) | ((unsigned)f2h(b.w) << 16);
      *(uint4*)(h2 + 4*tid) = make_uint4(p0, p1, p2, p3);
    } else {
      const ull* src = hbuf + (size_t)((t - 1) & 1)*1024 + 4*tid;
      const unsigned expect = (unsigned)t;
      ull v[4];
      unsigned done = 0;
      for (;;){
        #pragma unroll
        for (int j = 0; j < 4; ++j)
          if (!((done >> j) & 1u))
            v[j] = __hip_atomic_load(src + j, __ATOMIC_RELAXED, SCOPE_SYS);
        unsigned nd = done;
        #pragma unroll
        for (int j = 0; j < 4; ++j)
          if ((unsigned)(v[j] >> 32) == expect) nd |= (1u << j);
        if (nd == 15u) break;
        done = nd;
        __builtin_amdgcn_s_sleep(1);
      }
      *(uint4*)(h2 + 4*tid) = make_uint4((unsigned)v[0], (unsigned)v[1],
                                         (unsigned)v[2], (unsigned)v[3]);
    }
    __syncthreads();

    // per-lane h fragment: 4 x b128 = 32 h values as 16 f16-pairs
    uint4 hf[4];
    #pragma unroll
    for (int k = 0; k < 4; ++k)
      hf[k] = *(const uint4*)((const char*)h2 + 16*lane + 1024*k);
    // 6 dot rows; full butterfly so every lane ends with all 6 sums
    float acc[6];
    #pragma unroll
    for (int rr = 0; rr < 6; ++rr){
      int lr = 6*w + rr;
      const char* wrow = (const char*)Wl + lr*4096 + 16*lane;
      float a = 0.f;
      #pragma unroll
      for (int k = 0; k < 4; ++k){
        uint4 wv = *(const uint4*)(wrow + 1024*k);
        a = fdot2(wv.x, hf[k].x, a);
        a = fdot2(wv.y, hf[k].y, a);
        a = fdot2(wv.z, hf[k].z, a);
        a = fdot2(wv.w, hf[k].w, a);
      }
      #pragma unroll
      for (int off = 32; off; off >>= 1) a += __shfl_xor(a, off);
      acc[rr] = a;
    }
    // lanes 0,1 combine their output in parallel (fast-math serial shave)
    float hnew = 0.f;
    if (lane < 2){
      float r  = __fdividef(1.f, 1.f + __expf(-(gr + bhr + acc[0 + lane])));
      float z  = __fdividef(1.f, 1.f + __expf(-(gz + bhz + acc[2 + lane])));
      float e2 = __expf(2.f*(gn + r*(acc[4 + lane] + bhn)));
      float ng = __fdividef(e2 - 1.f, e2 + 1.f);
      hnew = (1.f - z)*ng + z*hold;
    }
    float hn1 = __shfl(hnew, 1);
    if (lane == 0){
      unsigned pair = (unsigned)f2h(hnew) | ((unsigned)f2h(hn1) << 16);
      ull pv = ((ull)(unsigned)(t + 1) << 32) | (ull)pair;
      __hip_atomic_store(hbuf + (size_t)(t & 1)*1024 + 4*wg + w, pv,
                         __ATOMIC_RELAXED, SCOPE_SYS);
    }
    if (lane < 2){
      xs[(size_t)t*2048 + hbase + 2*w + lane] = hnew;
      if (t == TS - 1) dout[4 + hbase + 2*w + lane] = hnew;
      hold = hnew;
    }
  }
}

// ---- head ----
__global__ void k_lin1(const float* __restrict__ xs, const float* __restrict__ W,
                       const float* __restrict__ B, float* __restrict__ y1){
  __shared__ float xT[32][36];
  __shared__ float wT[32][36];
  int tid = threadIdx.x;
  int m0 = blockIdx.y*32, n0 = blockIdx.x*32;
  int lm = tid >> 3, lk = (tid & 7)*4;
  int tx = tid & 15, ty = tid >> 4;
  float acc00=0.f, acc01=0.f, acc10=0.f, acc11=0.f;
  for (int k0 = 0; k0 < 2048; k0 += 32){
    float4 xv = make_float4(0.f,0.f,0.f,0.f);
    int tt = m0 + lm;
    if (tt < TS) xv = *(const float4*)(xs + (size_t)tt*2048 + k0 + lk);
    xT[lk+0][lm] = lrelu(xv.x); xT[lk+1][lm] = lrelu(xv.y);
    xT[lk+2][lm] = lrelu(xv.z); xT[lk+3][lm] = lrelu(xv.w);
    float4 wv = make_float4(0.f,0.f,0.f,0.f);
    int jj = n0 + lm;
    if (jj < 400) wv = *(const float4*)(W + (size_t)jj*2048 + k0 + lk);
    wT[lk+0][lm] = wv.x; wT[lk+1][lm] = wv.y; wT[lk+2][lm] = wv.z; wT[lk+3][lm] = wv.w;
    __syncthreads();
    #pragma unroll
    for (int k = 0; k < 32; ++k){
      float2 a = *(const float2*)&xT[k][2*ty];
      float2 b = *(const float2*)&wT[k][2*tx];
      acc00 = fmaf(a.x, b.x, acc00); acc01 = fmaf(a.x, b.y, acc01);
      acc10 = fmaf(a.y, b.x, acc10); acc11 = fmaf(a.y, b.y, acc11);
    }
    __syncthreads();
  }
  int t0 = m0 + 2*ty, j0 = n0 + 2*tx;
  if (t0 < TS){
    if (j0 < 400)   y1[t0*400 + j0]   = acc00 + B[j0];
    if (j0+1 < 400) y1[t0*400 + j0+1] = acc01 + B[j0+1];
  }
  if (t0+1 < TS){
    if (j0 < 400)   y1[(t0+1)*400 + j0]   = acc10 + B[j0];
    if (j0+1 < 400) y1[(t0+1)*400 + j0+1] = acc11 + B[j0+1];
  }
}

__global__ void k_bn3p(const float* __restrict__ y1, float* __restrict__ part){
  __shared__ float red[16];
  float s = 0.f, s2 = 0.f;
  for (int idx = blockIdx.x*256 + threadIdx.x; idx < TS*400; idx += 64*256){
    float v = y1[idx]; s += v; s2 += v*v;
  }
  s  = bred<false>(s, red);
  s2 = bred<false>(s2, red);
  if (threadIdx.x == 0){ part[blockIdx.x] = s; part[64 + blockIdx.x] = s2; }
}

__global__ void k_bn3f(const float* __restrict__ part, float* __restrict__ stats){
  int ln = threadIdx.x;
  float s = part[ln], s2 = part[64 + ln];
  #pragma unroll
  for (int off = 32; off; off >>= 1){ s += __shfl_xor(s, off); s2 += __shfl_xor(s2, off); }
  if (ln == 0){
    float m = s / (float)(TS*400);
    float var = s2 / (float)(TS*400) - m*m;
    stats[0] = m; stats[1] = rsqrtf(var + EPS);
  }
}

__global__ void k_x2(const float* __restrict__ y1, const float* __restrict__ stats,
                     const float* g3, const float* b3, const float* __restrict__ l2w,
                     const float* l2b, float* __restrict__ x2){
  int t = blockIdx.x, ln = threadIdx.x;
  float m = stats[0], iv = stats[1], g = g3[0], b = b3[0];
  float acc = 0.f;
  for (int j = ln; j < 400; j += 64)
    acc = fmaf(lrelu((y1[t*400 + j] - m)*iv*g + b), l2w[j], acc);
  #pragma unroll
  for (int off = 32; off; off >>= 1) acc += __shfl_xor(acc, off);
  if (ln == 0) x2[t] = lrelu(acc + l2b[0]);
}

__global__ void k_head(const float* __restrict__ x2, const float* __restrict__ last,
                       const float* __restrict__ l3w, const float* __restrict__ l3b,
                       const float* __restrict__ l4w, const float* __restrict__ l4b,
                       float* __restrict__ out){
  __shared__ float o1[50];
  int tid = threadIdx.x;
  if (tid < 50){
    float acc = l3b[tid];
    const float* wr = l3w + tid*507;
    for (int i = 0; i < TS; ++i) acc = fmaf(x2[i], wr[i], acc);
    for (int i = 0; i < 4; ++i)  acc = fmaf(last[i], wr[TS + i], acc);
    o1[tid] = lrelu(acc);
  }
  __syncthreads();
  if (tid < 4){
    float acc = l4b[tid];
    const float* wr = l4w + tid*50;
    for (int k = 0; k < 50; ++k) acc = fmaf(o1[k], wr[k], acc);
    out[tid] = acc;
  }
}

// ---- workspace layout (bytes) ----
#define OFF_BN2M    1024u
#define OFF_BN2I    1056u
#define OFF_BN3P    2048u
#define OFF_BN3S    2560u
#define OFF_W2      4096u
#define OFF_SCORE   12288u
#define OFF_X2      20480u
#define OFF_CTX     24576u
#define OFF_CB1     73728u      // cb1 (dead after conv2) is overlaid by hbuf (16KB)
#define OFF_HBUF    73728u
#define OFF_CB2     122880u
#define OFF_CP1     172032u
#define OFF_CB3     196608u
#define OFF_CB4     221184u
#define OFF_SEQ     245760u
#define OFF_GIHAT   274432u
#define OFF_XS      12636160u
#define OFF_Y1      16756736u

extern "C" void kernel_launch(void* const* d_in, const int* in_sizes, int n_in,
                              void* d_out, int out_size, void* d_ws, size_t ws_size,
                              hipStream_t stream){
  const float* last   = (const float*)d_in[0];
  const float* hidden = (const float*)d_in[1];
  const float* enc    = (const float*)d_in[2];
  const float* W1w = (const float*)d_in[3];
  const float* W1b = (const float*)d_in[4];
  const float* W2w = (const float*)d_in[5];
  const float* W2b = (const float*)d_in[6];
  const float* Vw  = (const float*)d_in[7];
  const float* Vb  = (const float*)d_in[8];
  const float* g1  = (const float*)d_in[9];
  const float* b1  = (const float*)d_in[10];
  const float* c1w = (const float*)d_in[11]; const float* c1b = (const float*)d_in[12];
  const float* c2w = (const float*)d_in[13]; const float* c2b = (const float*)d_in[14];
  const float* c3w = (const float*)d_in[15]; const float* c3b = (const float*)d_in[16];
  const float* c4w = (const float*)d_in[17]; const float* c4b = (const float*)d_in[18];
  const float* g2  = (const float*)d_in[19]; const float* b2  = (const float*)d_in[20];
  const float* Wi  = (const float*)d_in[21]; const float* Wh  = (const float*)d_in[22];
  const float* bi  = (const float*)d_in[23]; const float* bhp = (const float*)d_in[24];
  const float* l1w = (const float*)d_in[25]; const float* l1b = (const float*)d_in[26];
  const float* g3  = (const float*)d_in[27]; const float* b3  = (const float*)d_in[28];
  const float* l2w = (const float*)d_in[29]; const float* l2b = (const float*)d_in[30];
  const float* l3w = (const float*)d_in[31]; const float* l3b = (const float*)d_in[32];
  const float* l4w = (const float*)d_in[33]; const float* l4b = (const float*)d_in[34];
  float* out = (float*)d_out;
  char* ws = (char*)d_ws;

  float* bn2m  = (float*)(ws + OFF_BN2M);
  float* bn2i  = (float*)(ws + OFF_BN2I);
  float* bn3p  = (float*)(ws + OFF_BN3P);
  float* bn3s  = (float*)(ws + OFF_BN3S);
  float* w2v   = (float*)(ws + OFF_W2);
  float* score = (float*)(ws + OFF_SCORE);
  float* x2    = (float*)(ws + OFF_X2);
  float* ctx   = (float*)(ws + OFF_CTX);
  float* cb1   = (float*)(ws + OFF_CB1);
  ull*   hbuf  = (ull*)(ws + OFF_HBUF);
  float* cb2   = (float*)(ws + OFF_CB2);
  float* cp1   = (float*)(ws + OFF_CP1);
  float* cb3   = (float*)(ws + OFF_CB3);
  float* cb4   = (float*)(ws + OFF_CB4);
  float* seq   = (float*)(ws + OFF_SEQ);
  float* gihat = (float*)(ws + OFF_GIHAT);
  float* xs    = (float*)(ws + OFF_XS);
  float* y1    = (float*)(ws + OFF_Y1);

  k_w2<<<512, 256, 0, stream>>>(W2w, W2b, hidden, w2v);
  k_score<<<512, 256, 0, stream>>>(enc, W1w, W1b, Vw, Vb, w2v, score);
  k_softctx<<<1, 1024, 0, stream>>>(enc, score, g1, b1, ctx);

  k_conv<<<(6*2038 + 255)/256, 256, 0, stream>>>(ctx, 2048, cb1, 2038, c1w, c1b, 11);
  k_conv<<<(6*2028 + 255)/256, 256, 0, stream>>>(cb1, 2038, cb2, 2028, c2w, c2b, 11);
  // cb1 dead from here; clear stale tags in the overlaid hbuf (stream-ordered)
  hipMemsetAsync(hbuf, 0, 2*1024*sizeof(ull), stream);
  k_pool<<<(6*1014 + 255)/256, 256, 0, stream>>>(cb2, 2028, cp1, 1014);
  k_conv<<<(6*1010 + 255)/256, 256, 0, stream>>>(cp1, 1014, cb3, 1010, c3w, c3b, 5);
  k_conv<<<(6*1006 + 255)/256, 256, 0, stream>>>(cb3, 1010, cb4, 1006, c4w, c4b, 5);
  k_bn2stats<<<1, 256, 0, stream>>>(cb4, bn2m, bn2i);
  k_seq<<<12, 256, 0, stream>>>(cb4, bn2m, bn2i, g2, b2, seq);
  k_gihat<<<dim3(24, TS), 256, 0, stream>>>(seq, Wi, bi, gihat);

  hipFuncSetAttribute((const void*)k_gru, hipFuncAttributeMaxDynamicSharedMemorySize,
                      (int)GRU_SMEM);
  void* kargs[7] = {(void*)&Wh, (void*)&bhp, (void*)&hidden, (void*)&gihat,
                    (void*)&hbuf, (void*)&xs, (void*)&out};
  hipLaunchCooperativeKernel((const void*)k_gru, dim3(256), dim3(256), kargs,
                             (unsigned)GRU_SMEM, stream);

  k_lin1<<<dim3(13, 16), 256, 0, stream>>>(xs, l1w, l1b, y1);
  k_bn3p<<<64, 256, 0, stream>>>(y1, bn3p);
  k_bn3f<<<1, 64, 0, stream>>>(bn3p, bn3s);
  k_x2<<<TS, 64, 0, stream>>>(y1, bn3s, g3, b3, l2w, l2b, x2);
  k_head<<<1, 64, 0, stream>>>(x2, last, l3w, l3b, l4w, l4b, out);
}